// Round 3
// baseline (10524.122 us; speedup 1.0000x reference)
//
#include <hip/hip_runtime.h>

// ---------------------------------------------------------------------------
// LocationPredictor: embed -> biLSTM -> attention x3 -> masked conv x2 -> loss
// B=128 T=256 E=512 HSZ=1024 HD=512 VOCAB=2048 LVOCAB=11 K=6 STEPS=3
// Output d_out = 2 x float32 (loss, acc). Workspace ~112 MB.
// LSTM: cooperative persistent kernel, x-projection fused in-kernel, weights
// in registers as MFMA B-fragments, 64 KB LDS staging, per-dir grid barrier.
// ---------------------------------------------------------------------------

typedef _Float16 f16;
typedef __attribute__((ext_vector_type(8))) _Float16 f16x8;
typedef __attribute__((ext_vector_type(4))) float f32x4;

#define DEV __device__ __forceinline__

DEV void gload_lds16(const void* g, void* lds) {
  // async global->LDS, 16B per lane, LDS dst = uniform base + lane*16
  __builtin_amdgcn_global_load_lds(
      (const __attribute__((address_space(1))) unsigned*)g,
      (__attribute__((address_space(3))) unsigned*)lds, 16, 0, 0);
}
DEV float sigm(float x) { return 1.0f / (1.0f + __expf(-x)); }
DEV float tanh_(float x) { return 1.0f - 2.0f / (__expf(2.0f * x) + 1.0f); }
DEV unsigned pck(float a, float b) {
  union { unsigned u; f16 h[2]; } c; c.h[0] = (f16)a; c.h[1] = (f16)b; return c.u;
}

// ---------------------------------------------------------------------------
// Generic f16 GEMM: C[M][N] = A[M][K] * B[N][K]^T (+bias[n]); tiles 128x128,
// BK=32, global_load_lds staging, mfma_f32_16x16x32_f16. cmode 1->f16, 0->f32.
// ---------------------------------------------------------------------------
__global__ __launch_bounds__(256) void gemm_kernel(
    const f16* __restrict__ A, const f16* __restrict__ B,
    const float* __restrict__ bias, void* __restrict__ Cp,
    int M, int N, int K, int cmode) {
  __shared__ f16 As[128 * 32];
  __shared__ f16 Bs[128 * 32];
  const int tid = threadIdx.x;
  const int w = tid >> 6, l = tid & 63;
  const int m0 = blockIdx.x * 128, n0 = blockIdx.y * 128;
  const int wm = (w & 1) * 64, wn = (w >> 1) * 64;
  const int lr = l & 15, lq = l >> 4;
  const int srow = w * 32 + (l >> 2);
  const int kc8 = (l & 3) * 8;
  f32x4 acc[4][4];
#pragma unroll
  for (int i = 0; i < 4; ++i)
#pragma unroll
    for (int j = 0; j < 4; ++j) acc[i][j] = (f32x4){0.f, 0.f, 0.f, 0.f};

  for (int kt = 0; kt < K; kt += 32) {
    __syncthreads();
#pragma unroll
    for (int i = 0; i < 2; ++i) {
      gload_lds16(A + (long)(m0 + srow + i * 16) * K + kt + kc8,
                  &As[(w * 32 + i * 16) * 32]);
      gload_lds16(B + (long)(n0 + srow + i * 16) * K + kt + kc8,
                  &Bs[(w * 32 + i * 16) * 32]);
    }
    __syncthreads();
    f16x8 af[4], bf[4];
#pragma unroll
    for (int mi = 0; mi < 4; ++mi)
      af[mi] = *(const f16x8*)&As[(wm + mi * 16 + lr) * 32 + lq * 8];
#pragma unroll
    for (int ni = 0; ni < 4; ++ni)
      bf[ni] = *(const f16x8*)&Bs[(wn + ni * 16 + lr) * 32 + lq * 8];
#pragma unroll
    for (int mi = 0; mi < 4; ++mi)
#pragma unroll
      for (int ni = 0; ni < 4; ++ni)
        acc[mi][ni] =
            __builtin_amdgcn_mfma_f32_16x16x32_f16(af[mi], bf[ni], acc[mi][ni], 0, 0, 0);
  }
#pragma unroll
  for (int mi = 0; mi < 4; ++mi)
#pragma unroll
    for (int ni = 0; ni < 4; ++ni)
#pragma unroll
      for (int r = 0; r < 4; ++r) {
        const int m = m0 + wm + mi * 16 + lq * 4 + r;  // C row = quad*4+reg
        const int n = n0 + wn + ni * 16 + lr;          // C col = lane&15
        float v = acc[mi][ni][r];
        if (bias) v += bias[n];
        if (cmode) ((f16*)Cp)[(long)m * N + n] = (f16)v;
        else       ((float*)Cp)[(long)m * N + n] = v;
      }
}

// ---------------------------------------------------------------------------
// Cooperative biLSTM. 256 blocks x 256 threads (1 block/CU).
// block: d=blk>>7; idx=blk&127: ug=idx&63 (8 units), bh=idx>>6 (64 batch).
// Gate rows n = gt*8 + j (gt: i,f,g,o ; j: unit u0+j). W_ih & W_hh fragments
// live in registers (2 x 128 VGPR). Per step: stage x_t (64x512 f16) -> LDS,
// MFMA A; stage h_prev -> same LDS, MFMA B; gates via LDS-alias transpose;
// eltwise c/h; per-direction grid barrier.
// hg: [d][parity][128][512] f16. hidden: [b][t][1024] f16 (fwd | bwd).
// ---------------------------------------------------------------------------
__global__ __launch_bounds__(256, 1) void lstm_kernel(
    const f16* __restrict__ x16,
    const float* __restrict__ Wih_f, const float* __restrict__ Wih_b,
    const float* __restrict__ Whh_f, const float* __restrict__ Whh_b,
    const float* __restrict__ b_f, const float* __restrict__ b_b,
    f16* __restrict__ hg, f16* __restrict__ hidden, int* __restrict__ bar) {
  __shared__ f16 st[16 * 64 * 32];   // 64 KB staging [kt][m64][kk32]
  float* const gb = (float*)st;      // alias: gate buf [w*16+m][32] (8 KB)
  const int blk = blockIdx.x, tid = threadIdx.x;
  const int d = blk >> 7, idx = blk & 127;
  const int ug = idx & 63, bh = idx >> 6;
  const int u0 = ug * 8, b0 = bh * 64;
  const int w = tid >> 6, l = tid & 63;
  const int lr = l & 15, lq = l >> 4;
  const float* const Wih = d ? Wih_b : Wih_f;
  const float* const Whh = d ? Whh_b : Whh_f;
  const float* const bb = d ? b_b : b_f;

  // --- one-time: weights -> registers as MFMA B-fragments (f32 -> f16) ---
  f16x8 wih[16][2], whh[16][2];
#pragma unroll
  for (int kt = 0; kt < 16; ++kt)
#pragma unroll
    for (int nt = 0; nt < 2; ++nt) {
      const int n = nt * 16 + lr;                       // gate row within 32
      const long row = (long)((n >> 3) * 512 + u0 + (n & 7));
      const float* pi = Wih + row * 512 + kt * 32 + lq * 8;
      const float* ph = Whh + row * 512 + kt * 32 + lq * 8;
      f16x8 va, vb;
#pragma unroll
      for (int j = 0; j < 8; ++j) { va[j] = (f16)pi[j]; vb[j] = (f16)ph[j]; }
      wih[kt][nt] = va; whh[kt][nt] = vb;
    }
  const int bl = l >> 2, jp = (l & 3) * 2;   // eltwise: row bl, units jp,jp+1
  const int b_my = b0 + w * 16 + bl;
  const float bi0 = bb[u0 + jp],        bi1 = bb[u0 + jp + 1];
  const float bF0 = bb[512 + u0 + jp],  bF1 = bb[512 + u0 + jp + 1];
  const float bg0 = bb[1024 + u0 + jp], bg1 = bb[1024 + u0 + jp + 1];
  const float bo0 = bb[1536 + u0 + jp], bo1 = bb[1536 + u0 + jp + 1];
  float c0 = 0.f, c1 = 0.f;
  f16* const hbase = hg + (d * 2) * 65536;

#define STAGE64(SRCP)                                                         \
  {                                                                           \
    const f16* _s = (SRCP);                                                   \
    _Pragma("unroll") for (int k4 = 0; k4 < 4; ++k4) {                        \
      const int kt = w * 4 + k4;                                              \
      _Pragma("unroll") for (int i = 0; i < 4; ++i)                           \
        gload_lds16(_s + (long)(i * 16 + (l >> 2)) * 512 + kt * 32 + (l & 3) * 8, \
                    &st[(kt * 64 + i * 16) * 32]);                            \
    }                                                                         \
  }

  for (int s = 0; s < 256; ++s) {
    const int t = d ? (255 - s) : s;
    const f16* const hrd = hbase + (s & 1) * 65536;
    f16* const hwr = hbase + ((s + 1) & 1) * 65536;
    f32x4 a0 = (f32x4){0.f, 0.f, 0.f, 0.f}, a1 = (f32x4){0.f, 0.f, 0.f, 0.f};
    // phase A: x_t
    STAGE64(x16 + ((long)t * 128 + b0) * 512);
    __syncthreads();
#pragma unroll
    for (int kt = 0; kt < 16; ++kt) {
      const f16x8 av = *(const f16x8*)&st[(kt * 64 + w * 16 + lr) * 32 + lq * 8];
      a0 = __builtin_amdgcn_mfma_f32_16x16x32_f16(av, wih[kt][0], a0, 0, 0, 0);
      a1 = __builtin_amdgcn_mfma_f32_16x16x32_f16(av, wih[kt][1], a1, 0, 0, 0);
    }
    __syncthreads();
    // phase B: h_prev
    STAGE64(hrd + (long)b0 * 512);
    __syncthreads();
#pragma unroll
    for (int kt = 0; kt < 16; ++kt) {
      const f16x8 av = *(const f16x8*)&st[(kt * 64 + w * 16 + lr) * 32 + lq * 8];
      a0 = __builtin_amdgcn_mfma_f32_16x16x32_f16(av, whh[kt][0], a0, 0, 0, 0);
      a1 = __builtin_amdgcn_mfma_f32_16x16x32_f16(av, whh[kt][1], a1, 0, 0, 0);
    }
    __syncthreads();  // done reading st; safe to alias as gate buffer
#pragma unroll
    for (int r = 0; r < 4; ++r) {
      gb[(w * 16 + lq * 4 + r) * 32 + lr] = a0[r];
      gb[(w * 16 + lq * 4 + r) * 32 + 16 + lr] = a1[r];
    }
    __syncthreads();
    {
      const float* const gr = &gb[(w * 16 + bl) * 32];
      float gi = gr[jp] + bi0, gf = gr[8 + jp] + bF0;
      float gg = gr[16 + jp] + bg0, go = gr[24 + jp] + bo0;
      c0 = sigm(gf) * c0 + sigm(gi) * tanh_(gg);
      const float h0 = sigm(go) * tanh_(c0);
      gi = gr[jp + 1] + bi1; gf = gr[8 + jp + 1] + bF1;
      gg = gr[16 + jp + 1] + bg1; go = gr[24 + jp + 1] + bo1;
      c1 = sigm(gf) * c1 + sigm(gi) * tanh_(gg);
      const float h1 = sigm(go) * tanh_(c1);
      const unsigned hp = pck(h0, h1);
      *(unsigned*)&hwr[(b_my << 9) + u0 + jp] = hp;
      *(unsigned*)&hidden[((long)b_my * 256 + t) * 1024 + (d << 9) + u0 + jp] = hp;
    }
    // per-direction grid barrier
    __syncthreads();
    if (tid == 0) {
      __threadfence();  // release: L2 writeback (agent scope)
      const int arrived =
          __hip_atomic_fetch_add(&bar[d], 1, __ATOMIC_ACQ_REL, __HIP_MEMORY_SCOPE_AGENT);
      if (arrived == 127) {
        __hip_atomic_store(&bar[d], 0, __ATOMIC_RELAXED, __HIP_MEMORY_SCOPE_AGENT);
        __hip_atomic_store(&bar[2 + d], s + 1, __ATOMIC_RELEASE, __HIP_MEMORY_SCOPE_AGENT);
      } else {
        while (__hip_atomic_load(&bar[2 + d], __ATOMIC_ACQUIRE, __HIP_MEMORY_SCOPE_AGENT) <= s)
          __builtin_amdgcn_s_sleep(1);
      }
      __threadfence();  // acquire: invalidate L1/L2 before next h read
    }
    __syncthreads();
  }
#undef STAGE64
}

// ---------------------------------------------------------------------------
// Attention: score = hidden . ctrl, softmax over T, msg = att . hidden.
// One block per batch row. Writes msg (f32) and optionally cat=[msg||ctrl] f16.
// ---------------------------------------------------------------------------
__global__ __launch_bounds__(256) void att_kernel(
    const f16* __restrict__ hidden, const float* __restrict__ ctrl,
    const float* __restrict__ seq_mask, float* __restrict__ msg_out,
    f16* __restrict__ cat) {
  __shared__ float sc[256];
  __shared__ float red[4];
  __shared__ float ctl[1024];
  const int b = blockIdx.x, tid = threadIdx.x;
  const int w = tid >> 6, l = tid & 63;
  for (int i = tid; i < 1024; i += 256) ctl[i] = ctrl[b * 1024 + i];
  __syncthreads();
  float cl[16];
#pragma unroll
  for (int j = 0; j < 16; ++j) cl[j] = ctl[l + 64 * j];
  const f16* hb = hidden + (long)b * 262144;
  for (int t = w * 64; t < w * 64 + 64; ++t) {
    float s = 0.f;
#pragma unroll
    for (int j = 0; j < 16; ++j) s += (float)hb[t * 1024 + l + 64 * j] * cl[j];
#pragma unroll
    for (int off = 32; off; off >>= 1) s += __shfl_xor(s, off);
    if (l == 0) sc[t] = s;
  }
  __syncthreads();
  const float v = sc[tid] - 1e30f * (1.0f - seq_mask[b * 256 + tid]);
  float m = v;
#pragma unroll
  for (int off = 32; off; off >>= 1) m = fmaxf(m, __shfl_xor(m, off));
  if (l == 0) red[w] = m;
  __syncthreads();
  const float M = fmaxf(fmaxf(red[0], red[1]), fmaxf(red[2], red[3]));
  const float e = __expf(v - M);
  float ss = e;
#pragma unroll
  for (int off = 32; off; off >>= 1) ss += __shfl_xor(ss, off);
  __syncthreads();
  if (l == 0) red[w] = ss;
  __syncthreads();
  const float S = red[0] + red[1] + red[2] + red[3];
  sc[tid] = e / S;
  __syncthreads();
  const int hc = tid * 4;
  float a0 = 0.f, a1 = 0.f, a2 = 0.f, a3 = 0.f;
  for (int t = 0; t < 256; ++t) {
    const float at = sc[t];
    union { uint2 u; f16 h[4]; } q;
    q.u = *(const uint2*)&hb[t * 1024 + hc];
    a0 += at * (float)q.h[0]; a1 += at * (float)q.h[1];
    a2 += at * (float)q.h[2]; a3 += at * (float)q.h[3];
  }
  float* mo = msg_out + b * 1024 + hc;
  mo[0] = a0; mo[1] = a1; mo[2] = a2; mo[3] = a3;
  if (cat) {
    f16* cm = cat + (long)b * 2048 + hc;
    cm[0] = (f16)a0; cm[1] = (f16)a1; cm[2] = (f16)a2; cm[3] = (f16)a3;
    f16* cc = cat + (long)b * 2048 + 1024 + hc;
    cc[0] = (f16)ctl[hc]; cc[1] = (f16)ctl[hc + 1];
    cc[2] = (f16)ctl[hc + 2]; cc[3] = (f16)ctl[hc + 3];
  }
}

// l0[b][p][h] = sum_k map_emb[landmarks[b,p,k]][h]  (f16 out)
__global__ __launch_bounds__(256) void l0_kernel(
    const int* __restrict__ lm, const float* __restrict__ me, f16* __restrict__ l0) {
  const int bp = blockIdx.x, tid = threadIdx.x;
  const int h = tid * 4;
  int id[6];
#pragma unroll
  for (int k = 0; k < 6; ++k) id[k] = lm[bp * 6 + k];
  float a0 = 0.f, a1 = 0.f, a2 = 0.f, a3 = 0.f;
#pragma unroll
  for (int k = 0; k < 6; ++k) {
    const float* r = me + id[k] * 1024 + h;
    a0 += r[0]; a1 += r[1]; a2 += r[2]; a3 += r[3];
  }
  union { uint2 u; f16 hh[4]; } pk;
  pk.hh[0] = (f16)a0; pk.hh[1] = (f16)a1; pk.hh[2] = (f16)a2; pk.hh[3] = (f16)a3;
  *(uint2*)&l0[(long)bp * 1024 + h] = pk.u;
}

// patch[(b*16+p)][i*4+tap] = src[b][nbr(p,tap)][i], taps = up,left,right,down
__global__ __launch_bounds__(256) void patch_kernel(
    const f16* __restrict__ src, f16* __restrict__ patch) {
  const int bp = blockIdx.x, tid = threadIdx.x;
  const int b = bp >> 4, p = bp & 15, y = p >> 2, x = p & 3;
  const int base = b * 16;
  f16* pr = patch + (long)bp * 4096;
  for (int i = tid; i < 1024; i += 256) {
    union { uint2 u; f16 h[4]; } pk;
    pk.h[0] = (y > 0) ? src[(long)(base + p - 4) * 1024 + i] : (f16)0.f;
    pk.h[1] = (x > 0) ? src[(long)(base + p - 1) * 1024 + i] : (f16)0.f;
    pk.h[2] = (x < 3) ? src[(long)(base + p + 1) * 1024 + i] : (f16)0.f;
    pk.h[3] = (y < 3) ? src[(long)(base + p + 4) * 1024 + i] : (f16)0.f;
    *(uint2*)&pr[i * 4] = pk.u;
  }
}

// logits -> softmax -> log_softmax(prob) -> loss/acc (atomicAdd into la[2] f32)
__global__ __launch_bounds__(256) void logits_kernel(
    const f16* __restrict__ l0, const f16* __restrict__ l1, const f16* __restrict__ l2,
    const float* __restrict__ msgs, const int* __restrict__ ys, float* __restrict__ la) {
  __shared__ float lg[16];
  const int b = blockIdx.x, tid = threadIdx.x;
  const int p = tid >> 4, q = tid & 15;
  const float* m0 = msgs + b * 1024;
  const float* m1 = msgs + 131072 + b * 1024;
  const float* m2 = msgs + 262144 + b * 1024;
  const long row = (long)(b * 16 + p) * 1024;
  float part = 0.f;
  for (int i = 0; i < 64; ++i) {
    const int h = q + 16 * i;
    part += (float)l0[row + h] * m0[h] + (float)l1[row + h] * m1[h] +
            (float)l2[row + h] * m2[h];
  }
#pragma unroll
  for (int off = 8; off; off >>= 1) part += __shfl_xor(part, off, 16);
  if (q == 0) lg[p] = part;
  __syncthreads();
  if (tid == 0) {
    float mx = lg[0];
    for (int i = 1; i < 16; ++i) mx = fmaxf(mx, lg[i]);
    float pr[16]; float s = 0.f;
    for (int i = 0; i < 16; ++i) { pr[i] = __expf(lg[i] - mx); s += pr[i]; }
    for (int i = 0; i < 16; ++i) pr[i] /= s;
    float mx2 = pr[0];
    for (int i = 1; i < 16; ++i) mx2 = fmaxf(mx2, pr[i]);
    float s2 = 0.f;
    for (int i = 0; i < 16; ++i) s2 += __expf(pr[i] - mx2);
    const float lse = mx2 + __logf(s2);
    const int y = ys[b * 2] * 4 + ys[b * 2 + 1];
    const float logp = pr[y] - lse;
    int am = 0; float bv = pr[0];
    for (int i = 1; i < 16; ++i) if (pr[i] > bv) { bv = pr[i]; am = i; }
    atomicAdd(&la[0], -logp * (1.0f / 128.0f));
    atomicAdd(&la[1], (am == y) ? (1.0f / 128.0f) : 0.0f);
  }
}

// d_out is 2 x FLOAT32 (loss, acc) — reference outputs are f32 scalars.
__global__ void finalize_kernel(const float* __restrict__ la,
                                float* __restrict__ out) {
  if (threadIdx.x == 0) { out[0] = la[0]; out[1] = la[1]; }
}

// x16[t*128+b][e] = (f16) emb[Xs[b][t]][e]
__global__ __launch_bounds__(256) void embed_kernel(
    const int* __restrict__ Xs, const float* __restrict__ emb, f16* __restrict__ x16) {
  const int m = blockIdx.x, tid = threadIdx.x;
  const int t = m >> 7, b = m & 127;
  const int v = Xs[b * 256 + t];
  const int e = tid * 2;
  const float2 f = *(const float2*)&emb[(long)v * 512 + e];
  *(unsigned*)&x16[(long)m * 512 + e] = pck(f.x, f.y);
}

// post-LSTM weight prep (targets alias the dead x16 region):
// updW16 f16 [1024][2048]; w4 f16 [1024][4096] = cross taps (0,1),(1,0),(1,2),(2,1)
__global__ __launch_bounds__(256) void prep2_kernel(
    const float* __restrict__ upd_W, const float* __restrict__ conv_w,
    f16* __restrict__ updW16, f16* __restrict__ w4) {
  const int idx = blockIdx.x * 256 + threadIdx.x;  // 0..4194303
  if (idx < 2097152) updW16[idx] = (f16)upd_W[idx];
  const int o = idx >> 12, r = idx & 4095, i = r >> 2, tp = r & 3;
  w4[idx] = (f16)conv_w[(long)(o * 1024 + i) * 9 + 1 + 2 * tp];
}

// zero h state / barrier / loss accum, init controller = broadcast(feat_ctrl)
__global__ __launch_bounds__(256) void init_kernel(
    f16* __restrict__ hg, int* __restrict__ bar, float* __restrict__ la,
    float* __restrict__ ctrlA, const float* __restrict__ feat) {
  const int idx = blockIdx.x * 256 + threadIdx.x;  // 0..131071
  ((unsigned*)hg)[idx] = 0u;
  ctrlA[idx] = feat[idx & 1023];
  if (idx < 16) bar[idx] = 0;
  if (idx < 2) la[idx] = 0.f;
}

__global__ void fail_kernel(float* out, int mb) {
  if (threadIdx.x == 0) { out[0] = 12344.0f; out[1] = (float)mb; }
}

// ---------------------------------------------------------------------------
extern "C" void kernel_launch(void* const* d_in, const int* in_sizes, int n_in,
                              void* d_out, int out_size, void* d_ws, size_t ws_size,
                              hipStream_t stream) {
  (void)in_sizes; (void)n_in; (void)out_size;
  const int*   Xs      = (const int*)d_in[0];
  const float* seqmask = (const float*)d_in[1];
  const int*   lm      = (const int*)d_in[2];
  const int*   ys      = (const int*)d_in[3];
  const float* emb     = (const float*)d_in[4];
  const float* W_ih_f  = (const float*)d_in[5];
  const float* W_hh_f  = (const float*)d_in[6];
  const float* b_f     = (const float*)d_in[7];
  const float* W_ih_b  = (const float*)d_in[8];
  const float* W_hh_b  = (const float*)d_in[9];
  const float* b_b     = (const float*)d_in[10];
  const float* feat    = (const float*)d_in[11];
  const float* upd_W   = (const float*)d_in[12];
  const float* upd_b   = (const float*)d_in[13];
  const float* mapemb  = (const float*)d_in[14];
  const float* conv_w  = (const float*)d_in[15];
  float* out = (float*)d_out;  // 2 x f32 (loss, acc)
  char* ws = (char*)d_ws;
  size_t off = 0;
  auto alloc = [&](size_t bytes) {
    void* p = ws + off; off += (bytes + 255) & ~(size_t)255; return p;
  };
  f16*   x16    = (f16*)alloc(33554432);   // [t*128+b][512] f16; dead post-LSTM
  f16*   hid    = (f16*)alloc(67108864);   // hidden f16 [b][t][1024]
  f16*   hgb    = (f16*)alloc(524288);     // h state [d][parity][128][512]
  int*   bar    = (int*)alloc(256);        // barrier cnt[2], gen[2]
  float* la     = (float*)alloc(256);      // loss/acc f32 accum
  float* ctrlA  = (float*)alloc(524288);
  float* ctrlB  = (float*)alloc(524288);
  float* msgs   = (float*)alloc(1572864);  // 3 x [128][1024] f32
  f16*   cat    = (f16*)alloc(524288);     // [128][2048] f16
  f16*   l0b    = (f16*)alloc(4194304);    // [b*16+p][1024] f16
  f16*   l1b    = (f16*)alloc(4194304);
  f16*   l2b    = (f16*)alloc(4194304);
  // aliases into the x16 region (only used after the LSTM):
  f16*   patch  = x16;                      // [2048][4096] f16, 16 MB
  f16*   w416   = x16 + 8388608;            // [1024][4096] f16, 8 MB
  f16*   updW16 = x16 + 12582912;           // [1024][2048] f16, 4 MB
  if (ws_size < off) {                      // ~112 MB needed
    fail_kernel<<<1, 64, 0, stream>>>(out, (int)(off >> 20));
    return;
  }

  init_kernel<<<512, 256, 0, stream>>>(hgb, bar, la, ctrlA, feat);
  embed_kernel<<<32768, 256, 0, stream>>>(Xs, emb, x16);
  {
    void* args[] = {(void*)&x16, (void*)&W_ih_f, (void*)&W_ih_b,
                    (void*)&W_hh_f, (void*)&W_hh_b, (void*)&b_f, (void*)&b_b,
                    (void*)&hgb, (void*)&hid, (void*)&bar};
    hipLaunchCooperativeKernel((void*)lstm_kernel, dim3(256), dim3(256), args, 0, stream);
  }
  prep2_kernel<<<16384, 256, 0, stream>>>(upd_W, conv_w, updW16, w416);
  // landmark path
  l0_kernel<<<2048, 256, 0, stream>>>(lm, mapemb, l0b);
  patch_kernel<<<2048, 256, 0, stream>>>(l0b, patch);
  gemm_kernel<<<dim3(16, 8), 256, 0, stream>>>(patch, w416, nullptr, l1b,
                                               2048, 1024, 4096, 1);
  patch_kernel<<<2048, 256, 0, stream>>>(l1b, patch);
  gemm_kernel<<<dim3(16, 8), 256, 0, stream>>>(patch, w416, nullptr, l2b,
                                               2048, 1024, 4096, 1);
  // attention x3 (controller ping-pong); ctrl' = cat @ upd_W^T + upd_b (f32)
  att_kernel<<<128, 256, 0, stream>>>(hid, ctrlA, seqmask, msgs, cat);
  gemm_kernel<<<dim3(1, 8), 256, 0, stream>>>(cat, updW16, upd_b, ctrlB,
                                              128, 1024, 2048, 0);
  att_kernel<<<128, 256, 0, stream>>>(hid, ctrlB, seqmask, msgs + 131072, cat);
  gemm_kernel<<<dim3(1, 8), 256, 0, stream>>>(cat, updW16, upd_b, ctrlA,
                                              128, 1024, 2048, 0);
  att_kernel<<<128, 256, 0, stream>>>(hid, ctrlA, seqmask, msgs + 262144, nullptr);
  logits_kernel<<<128, 256, 0, stream>>>(l0b, l1b, l2b, msgs, ys, la);
  finalize_kernel<<<1, 64, 0, stream>>>(la, out);
}

// Round 4
// 2762.348 us; speedup vs baseline: 3.8098x; 3.8098x over previous
//
#include <hip/hip_runtime.h>

// ---------------------------------------------------------------------------
// LocationPredictor: embed -> biLSTM -> attention x3 -> masked conv x2 -> loss
// B=128 T=256 E=512 HSZ=1024 HD=512 VOCAB=2048 LVOCAB=11 K=6 STEPS=3
// Output d_out = 2 x float32 (loss, acc). Workspace ~112 MB.
// LSTM: cooperative persistent kernel; h exchanged via system-coherent (sc0|sc1)
// stores + MALL-reading staged loads; flat flag-array sub-barriers (no fences,
// no L2 flush/invalidate -> x tiles stay L2-resident).
// ---------------------------------------------------------------------------

typedef _Float16 f16;
typedef __attribute__((ext_vector_type(8))) _Float16 f16x8;
typedef __attribute__((ext_vector_type(4))) float f32x4;

#define DEV __device__ __forceinline__

DEV void gload_lds16(const void* g, void* lds) {
  // async global->LDS, 16B per lane, LDS dst = uniform base + lane*16 (cached)
  __builtin_amdgcn_global_load_lds(
      (const __attribute__((address_space(1))) unsigned*)g,
      (__attribute__((address_space(3))) unsigned*)lds, 16, 0, 0);
}
DEV void gload_lds16c(const void* g, void* lds) {
  // coherent variant: aux = SC0|SC1 (1|16) -> bypass L1/L2, read MALL
  __builtin_amdgcn_global_load_lds(
      (const __attribute__((address_space(1))) unsigned*)g,
      (__attribute__((address_space(3))) unsigned*)lds, 16, 0, 17);
}
DEV float sigm(float x) { return 1.0f / (1.0f + __expf(-x)); }
DEV float tanh_(float x) { return 1.0f - 2.0f / (__expf(2.0f * x) + 1.0f); }
DEV unsigned pck(float a, float b) {
  union { unsigned u; f16 h[2]; } c; c.h[0] = (f16)a; c.h[1] = (f16)b; return c.u;
}

// ---------------------------------------------------------------------------
// Generic f16 GEMM: C[M][N] = A[M][K] * B[N][K]^T (+bias[n]); tiles 128x128,
// BK=32, global_load_lds staging, mfma_f32_16x16x32_f16. cmode 1->f16, 0->f32.
// ---------------------------------------------------------------------------
__global__ __launch_bounds__(256) void gemm_kernel(
    const f16* __restrict__ A, const f16* __restrict__ B,
    const float* __restrict__ bias, void* __restrict__ Cp,
    int M, int N, int K, int cmode) {
  __shared__ f16 As[128 * 32];
  __shared__ f16 Bs[128 * 32];
  const int tid = threadIdx.x;
  const int w = tid >> 6, l = tid & 63;
  const int m0 = blockIdx.x * 128, n0 = blockIdx.y * 128;
  const int wm = (w & 1) * 64, wn = (w >> 1) * 64;
  const int lr = l & 15, lq = l >> 4;
  const int srow = w * 32 + (l >> 2);
  const int kc8 = (l & 3) * 8;
  f32x4 acc[4][4];
#pragma unroll
  for (int i = 0; i < 4; ++i)
#pragma unroll
    for (int j = 0; j < 4; ++j) acc[i][j] = (f32x4){0.f, 0.f, 0.f, 0.f};

  for (int kt = 0; kt < K; kt += 32) {
    __syncthreads();
#pragma unroll
    for (int i = 0; i < 2; ++i) {
      gload_lds16(A + (long)(m0 + srow + i * 16) * K + kt + kc8,
                  &As[(w * 32 + i * 16) * 32]);
      gload_lds16(B + (long)(n0 + srow + i * 16) * K + kt + kc8,
                  &Bs[(w * 32 + i * 16) * 32]);
    }
    __syncthreads();
    f16x8 af[4], bf[4];
#pragma unroll
    for (int mi = 0; mi < 4; ++mi)
      af[mi] = *(const f16x8*)&As[(wm + mi * 16 + lr) * 32 + lq * 8];
#pragma unroll
    for (int ni = 0; ni < 4; ++ni)
      bf[ni] = *(const f16x8*)&Bs[(wn + ni * 16 + lr) * 32 + lq * 8];
#pragma unroll
    for (int mi = 0; mi < 4; ++mi)
#pragma unroll
      for (int ni = 0; ni < 4; ++ni)
        acc[mi][ni] =
            __builtin_amdgcn_mfma_f32_16x16x32_f16(af[mi], bf[ni], acc[mi][ni], 0, 0, 0);
  }
#pragma unroll
  for (int mi = 0; mi < 4; ++mi)
#pragma unroll
    for (int ni = 0; ni < 4; ++ni)
#pragma unroll
      for (int r = 0; r < 4; ++r) {
        const int m = m0 + wm + mi * 16 + lq * 4 + r;  // C row = quad*4+reg
        const int n = n0 + wn + ni * 16 + lr;          // C col = lane&15
        float v = acc[mi][ni][r];
        if (bias) v += bias[n];
        if (cmode) ((f16*)Cp)[(long)m * N + n] = (f16)v;
        else       ((float*)Cp)[(long)m * N + n] = v;
      }
}

// ---------------------------------------------------------------------------
// Cooperative biLSTM. 256 blocks x 256 threads (1 block/CU).
// block: d=blk>>7; idx=blk&127: ug=idx&63 (8 units), bh=idx>>6 (64 batch).
// W_ih & W_hh fragments in registers. Per step: stage x_t -> LDS (cached),
// MFMA; stage h_prev -> LDS (coherent, MALL); MFMA; eltwise; flag sub-barrier.
// h stores are system-scope relaxed atomics (write-through to MALL). Flags:
// bar[d*128 + bh*64 + ug] = s+1 (monotone, no reset). 4 independent
// sub-barriers of 64 blocks each (a block only reads h rows of its own bh).
// ---------------------------------------------------------------------------
__global__ __launch_bounds__(256, 1) void lstm_kernel(
    const f16* __restrict__ x16,
    const float* __restrict__ Wih_f, const float* __restrict__ Wih_b,
    const float* __restrict__ Whh_f, const float* __restrict__ Whh_b,
    const float* __restrict__ b_f, const float* __restrict__ b_b,
    f16* __restrict__ hg, f16* __restrict__ hidden, int* __restrict__ bar) {
  __shared__ f16 st[16 * 64 * 32];   // 64 KB staging [kt][m64][kk32]
  float* const gb = (float*)st;      // alias: gate buf [w*16+m][32] (8 KB)
  const int blk = blockIdx.x, tid = threadIdx.x;
  const int d = blk >> 7, idx = blk & 127;
  const int ug = idx & 63, bh = idx >> 6;
  const int u0 = ug * 8, b0 = bh * 64;
  const int w = tid >> 6, l = tid & 63;
  const int lr = l & 15, lq = l >> 4;
  const float* const Wih = d ? Wih_b : Wih_f;
  const float* const Whh = d ? Whh_b : Whh_f;
  const float* const bb = d ? b_b : b_f;

  // --- one-time: weights -> registers as MFMA B-fragments (f32 -> f16) ---
  f16x8 wih[16][2], whh[16][2];
#pragma unroll
  for (int kt = 0; kt < 16; ++kt)
#pragma unroll
    for (int nt = 0; nt < 2; ++nt) {
      const int n = nt * 16 + lr;                       // gate row within 32
      const long row = (long)((n >> 3) * 512 + u0 + (n & 7));
      const float* pi = Wih + row * 512 + kt * 32 + lq * 8;
      const float* ph = Whh + row * 512 + kt * 32 + lq * 8;
      f16x8 va, vb;
#pragma unroll
      for (int j = 0; j < 8; ++j) { va[j] = (f16)pi[j]; vb[j] = (f16)ph[j]; }
      wih[kt][nt] = va; whh[kt][nt] = vb;
    }
  const int bl = l >> 2, jp = (l & 3) * 2;   // eltwise: row bl, units jp,jp+1
  const int b_my = b0 + w * 16 + bl;
  const float bi0 = bb[u0 + jp],        bi1 = bb[u0 + jp + 1];
  const float bF0 = bb[512 + u0 + jp],  bF1 = bb[512 + u0 + jp + 1];
  const float bg0 = bb[1024 + u0 + jp], bg1 = bb[1024 + u0 + jp + 1];
  const float bo0 = bb[1536 + u0 + jp], bo1 = bb[1536 + u0 + jp + 1];
  float c0 = 0.f, c1 = 0.f;
  f16* const hbase = hg + (d * 2) * 65536;
  int* const myflag = &bar[(d << 7) + (bh << 6) + ug];
  int* const pollp = &bar[(d << 7) + (bh << 6) + (tid & 63)];

#define STAGE64(SRCP, LOADER)                                                 \
  {                                                                           \
    const f16* _s = (SRCP);                                                   \
    _Pragma("unroll") for (int k4 = 0; k4 < 4; ++k4) {                        \
      const int kt = w * 4 + k4;                                              \
      _Pragma("unroll") for (int i = 0; i < 4; ++i)                           \
        LOADER(_s + (long)(i * 16 + (l >> 2)) * 512 + kt * 32 + (l & 3) * 8,  \
               &st[(kt * 64 + i * 16) * 32]);                                 \
    }                                                                         \
  }

  for (int s = 0; s < 256; ++s) {
    const int t = d ? (255 - s) : s;
    const f16* const hrd = hbase + (s & 1) * 65536;
    f16* const hwr = hbase + ((s + 1) & 1) * 65536;
    f32x4 a0 = (f32x4){0.f, 0.f, 0.f, 0.f}, a1 = (f32x4){0.f, 0.f, 0.f, 0.f};
    // phase A: x_t (L2-cached; no invalidations anywhere so it stays hot)
    STAGE64(x16 + ((long)t * 128 + b0) * 512, gload_lds16);
    __syncthreads();
#pragma unroll
    for (int kt = 0; kt < 16; ++kt) {
      const f16x8 av = *(const f16x8*)&st[(kt * 64 + w * 16 + lr) * 32 + lq * 8];
      a0 = __builtin_amdgcn_mfma_f32_16x16x32_f16(av, wih[kt][0], a0, 0, 0, 0);
      a1 = __builtin_amdgcn_mfma_f32_16x16x32_f16(av, wih[kt][1], a1, 0, 0, 0);
    }
    __syncthreads();
    // phase B: h_prev (coherent: read the MALL, never cache locally)
    STAGE64(hrd + (long)b0 * 512, gload_lds16c);
    __syncthreads();
#pragma unroll
    for (int kt = 0; kt < 16; ++kt) {
      const f16x8 av = *(const f16x8*)&st[(kt * 64 + w * 16 + lr) * 32 + lq * 8];
      a0 = __builtin_amdgcn_mfma_f32_16x16x32_f16(av, whh[kt][0], a0, 0, 0, 0);
      a1 = __builtin_amdgcn_mfma_f32_16x16x32_f16(av, whh[kt][1], a1, 0, 0, 0);
    }
    __syncthreads();  // done reading st; safe to alias as gate buffer
#pragma unroll
    for (int r = 0; r < 4; ++r) {
      gb[(w * 16 + lq * 4 + r) * 32 + lr] = a0[r];
      gb[(w * 16 + lq * 4 + r) * 32 + 16 + lr] = a1[r];
    }
    __syncthreads();
    {
      const float* const gr = &gb[(w * 16 + bl) * 32];
      float gi = gr[jp] + bi0, gf = gr[8 + jp] + bF0;
      float gg = gr[16 + jp] + bg0, go = gr[24 + jp] + bo0;
      c0 = sigm(gf) * c0 + sigm(gi) * tanh_(gg);
      const float h0 = sigm(go) * tanh_(c0);
      gi = gr[jp + 1] + bi1; gf = gr[8 + jp + 1] + bF1;
      gg = gr[16 + jp + 1] + bg1; go = gr[24 + jp + 1] + bo1;
      c1 = sigm(gf) * c1 + sigm(gi) * tanh_(gg);
      const float h1 = sigm(go) * tanh_(c1);
      const unsigned hp = pck(h0, h1);
      // h exchange: write-through to the coherence point (no L2 flush needed)
      __hip_atomic_store((unsigned*)&hwr[(b_my << 9) + u0 + jp], hp,
                         __ATOMIC_RELAXED, __HIP_MEMORY_SCOPE_SYSTEM);
      *(unsigned*)&hidden[((long)b_my * 256 + t) * 1024 + (d << 9) + u0 + jp] = hp;
    }
    // flag sub-barrier: my h stores acked at MALL -> publish s+1; wave0 polls
    // the 64 writer blocks of my (d, bh).
    __builtin_amdgcn_s_waitcnt(0);   // drain my vmem (h store reached MALL)
    __syncthreads();                 // all 256 threads drained
    if (tid < 64) {
      if (tid == 0)
        __hip_atomic_store(myflag, s + 1, __ATOMIC_RELAXED,
                           __HIP_MEMORY_SCOPE_SYSTEM);
      while (__hip_atomic_load(pollp, __ATOMIC_RELAXED,
                               __HIP_MEMORY_SCOPE_SYSTEM) <= s)
        __builtin_amdgcn_s_sleep(2);
    }
    __syncthreads();
  }
#undef STAGE64
}

// ---------------------------------------------------------------------------
// Attention: score = hidden . ctrl, softmax over T, msg = att . hidden.
// One block per batch row. Writes msg (f32) and optionally cat=[msg||ctrl] f16.
// ---------------------------------------------------------------------------
__global__ __launch_bounds__(256) void att_kernel(
    const f16* __restrict__ hidden, const float* __restrict__ ctrl,
    const float* __restrict__ seq_mask, float* __restrict__ msg_out,
    f16* __restrict__ cat) {
  __shared__ float sc[256];
  __shared__ float red[4];
  __shared__ float ctl[1024];
  const int b = blockIdx.x, tid = threadIdx.x;
  const int w = tid >> 6, l = tid & 63;
  for (int i = tid; i < 1024; i += 256) ctl[i] = ctrl[b * 1024 + i];
  __syncthreads();
  float cl[16];
#pragma unroll
  for (int j = 0; j < 16; ++j) cl[j] = ctl[l + 64 * j];
  const f16* hb = hidden + (long)b * 262144;
  for (int t = w * 64; t < w * 64 + 64; ++t) {
    float s = 0.f;
#pragma unroll
    for (int j = 0; j < 16; ++j) s += (float)hb[t * 1024 + l + 64 * j] * cl[j];
#pragma unroll
    for (int off = 32; off; off >>= 1) s += __shfl_xor(s, off);
    if (l == 0) sc[t] = s;
  }
  __syncthreads();
  const float v = sc[tid] - 1e30f * (1.0f - seq_mask[b * 256 + tid]);
  float m = v;
#pragma unroll
  for (int off = 32; off; off >>= 1) m = fmaxf(m, __shfl_xor(m, off));
  if (l == 0) red[w] = m;
  __syncthreads();
  const float M = fmaxf(fmaxf(red[0], red[1]), fmaxf(red[2], red[3]));
  const float e = __expf(v - M);
  float ss = e;
#pragma unroll
  for (int off = 32; off; off >>= 1) ss += __shfl_xor(ss, off);
  __syncthreads();
  if (l == 0) red[w] = ss;
  __syncthreads();
  const float S = red[0] + red[1] + red[2] + red[3];
  sc[tid] = e / S;
  __syncthreads();
  const int hc = tid * 4;
  float a0 = 0.f, a1 = 0.f, a2 = 0.f, a3 = 0.f;
  for (int t = 0; t < 256; ++t) {
    const float at = sc[t];
    union { uint2 u; f16 h[4]; } q;
    q.u = *(const uint2*)&hb[t * 1024 + hc];
    a0 += at * (float)q.h[0]; a1 += at * (float)q.h[1];
    a2 += at * (float)q.h[2]; a3 += at * (float)q.h[3];
  }
  float* mo = msg_out + b * 1024 + hc;
  mo[0] = a0; mo[1] = a1; mo[2] = a2; mo[3] = a3;
  if (cat) {
    f16* cm = cat + (long)b * 2048 + hc;
    cm[0] = (f16)a0; cm[1] = (f16)a1; cm[2] = (f16)a2; cm[3] = (f16)a3;
    f16* cc = cat + (long)b * 2048 + 1024 + hc;
    cc[0] = (f16)ctl[hc]; cc[1] = (f16)ctl[hc + 1];
    cc[2] = (f16)ctl[hc + 2]; cc[3] = (f16)ctl[hc + 3];
  }
}

// l0[b][p][h] = sum_k map_emb[landmarks[b,p,k]][h]  (f16 out)
__global__ __launch_bounds__(256) void l0_kernel(
    const int* __restrict__ lm, const float* __restrict__ me, f16* __restrict__ l0) {
  const int bp = blockIdx.x, tid = threadIdx.x;
  const int h = tid * 4;
  int id[6];
#pragma unroll
  for (int k = 0; k < 6; ++k) id[k] = lm[bp * 6 + k];
  float a0 = 0.f, a1 = 0.f, a2 = 0.f, a3 = 0.f;
#pragma unroll
  for (int k = 0; k < 6; ++k) {
    const float* r = me + id[k] * 1024 + h;
    a0 += r[0]; a1 += r[1]; a2 += r[2]; a3 += r[3];
  }
  union { uint2 u; f16 hh[4]; } pk;
  pk.hh[0] = (f16)a0; pk.hh[1] = (f16)a1; pk.hh[2] = (f16)a2; pk.hh[3] = (f16)a3;
  *(uint2*)&l0[(long)bp * 1024 + h] = pk.u;
}

// patch[(b*16+p)][i*4+tap] = src[b][nbr(p,tap)][i], taps = up,left,right,down
__global__ __launch_bounds__(256) void patch_kernel(
    const f16* __restrict__ src, f16* __restrict__ patch) {
  const int bp = blockIdx.x, tid = threadIdx.x;
  const int b = bp >> 4, p = bp & 15, y = p >> 2, x = p & 3;
  const int base = b * 16;
  f16* pr = patch + (long)bp * 4096;
  for (int i = tid; i < 1024; i += 256) {
    union { uint2 u; f16 h[4]; } pk;
    pk.h[0] = (y > 0) ? src[(long)(base + p - 4) * 1024 + i] : (f16)0.f;
    pk.h[1] = (x > 0) ? src[(long)(base + p - 1) * 1024 + i] : (f16)0.f;
    pk.h[2] = (x < 3) ? src[(long)(base + p + 1) * 1024 + i] : (f16)0.f;
    pk.h[3] = (y < 3) ? src[(long)(base + p + 4) * 1024 + i] : (f16)0.f;
    *(uint2*)&pr[i * 4] = pk.u;
  }
}

// logits -> softmax -> log_softmax(prob) -> loss/acc (atomicAdd into la[2] f32)
__global__ __launch_bounds__(256) void logits_kernel(
    const f16* __restrict__ l0, const f16* __restrict__ l1, const f16* __restrict__ l2,
    const float* __restrict__ msgs, const int* __restrict__ ys, float* __restrict__ la) {
  __shared__ float lg[16];
  const int b = blockIdx.x, tid = threadIdx.x;
  const int p = tid >> 4, q = tid & 15;
  const float* m0 = msgs + b * 1024;
  const float* m1 = msgs + 131072 + b * 1024;
  const float* m2 = msgs + 262144 + b * 1024;
  const long row = (long)(b * 16 + p) * 1024;
  float part = 0.f;
  for (int i = 0; i < 64; ++i) {
    const int h = q + 16 * i;
    part += (float)l0[row + h] * m0[h] + (float)l1[row + h] * m1[h] +
            (float)l2[row + h] * m2[h];
  }
#pragma unroll
  for (int off = 8; off; off >>= 1) part += __shfl_xor(part, off, 16);
  if (q == 0) lg[p] = part;
  __syncthreads();
  if (tid == 0) {
    float mx = lg[0];
    for (int i = 1; i < 16; ++i) mx = fmaxf(mx, lg[i]);
    float pr[16]; float s = 0.f;
    for (int i = 0; i < 16; ++i) { pr[i] = __expf(lg[i] - mx); s += pr[i]; }
    for (int i = 0; i < 16; ++i) pr[i] /= s;
    float mx2 = pr[0];
    for (int i = 1; i < 16; ++i) mx2 = fmaxf(mx2, pr[i]);
    float s2 = 0.f;
    for (int i = 0; i < 16; ++i) s2 += __expf(pr[i] - mx2);
    const float lse = mx2 + __logf(s2);
    const int y = ys[b * 2] * 4 + ys[b * 2 + 1];
    const float logp = pr[y] - lse;
    int am = 0; float bv = pr[0];
    for (int i = 1; i < 16; ++i) if (pr[i] > bv) { bv = pr[i]; am = i; }
    atomicAdd(&la[0], -logp * (1.0f / 128.0f));
    atomicAdd(&la[1], (am == y) ? (1.0f / 128.0f) : 0.0f);
  }
}

// d_out is 2 x FLOAT32 (loss, acc)
__global__ void finalize_kernel(const float* __restrict__ la,
                                float* __restrict__ out) {
  if (threadIdx.x == 0) { out[0] = la[0]; out[1] = la[1]; }
}

// x16[t*128+b][e] = (f16) emb[Xs[b][t]][e]
__global__ __launch_bounds__(256) void embed_kernel(
    const int* __restrict__ Xs, const float* __restrict__ emb, f16* __restrict__ x16) {
  const int m = blockIdx.x, tid = threadIdx.x;
  const int t = m >> 7, b = m & 127;
  const int v = Xs[b * 256 + t];
  const int e = tid * 2;
  const float2 f = *(const float2*)&emb[(long)v * 512 + e];
  *(unsigned*)&x16[(long)m * 512 + e] = pck(f.x, f.y);
}

// post-LSTM weight prep (targets alias the dead x16 region):
// updW16 f16 [1024][2048]; w4 f16 [1024][4096] = cross taps (0,1),(1,0),(1,2),(2,1)
__global__ __launch_bounds__(256) void prep2_kernel(
    const float* __restrict__ upd_W, const float* __restrict__ conv_w,
    f16* __restrict__ updW16, f16* __restrict__ w4) {
  const int idx = blockIdx.x * 256 + threadIdx.x;  // 0..4194303
  if (idx < 2097152) updW16[idx] = (f16)upd_W[idx];
  const int o = idx >> 12, r = idx & 4095, i = r >> 2, tp = r & 3;
  w4[idx] = (f16)conv_w[(long)(o * 1024 + i) * 9 + 1 + 2 * tp];
}

// zero h state / flags / loss accum, init controller = broadcast(feat_ctrl)
__global__ __launch_bounds__(256) void init_kernel(
    f16* __restrict__ hg, int* __restrict__ bar, float* __restrict__ la,
    float* __restrict__ ctrlA, const float* __restrict__ feat) {
  const int idx = blockIdx.x * 256 + threadIdx.x;  // 0..131071
  ((unsigned*)hg)[idx] = 0u;
  ctrlA[idx] = feat[idx & 1023];
  if (idx < 256) bar[idx] = 0;
  if (idx < 2) la[idx] = 0.f;
}

__global__ void fail_kernel(float* out, int mb) {
  if (threadIdx.x == 0) { out[0] = 12344.0f; out[1] = (float)mb; }
}

// ---------------------------------------------------------------------------
extern "C" void kernel_launch(void* const* d_in, const int* in_sizes, int n_in,
                              void* d_out, int out_size, void* d_ws, size_t ws_size,
                              hipStream_t stream) {
  (void)in_sizes; (void)n_in; (void)out_size;
  const int*   Xs      = (const int*)d_in[0];
  const float* seqmask = (const float*)d_in[1];
  const int*   lm      = (const int*)d_in[2];
  const int*   ys      = (const int*)d_in[3];
  const float* emb     = (const float*)d_in[4];
  const float* W_ih_f  = (const float*)d_in[5];
  const float* W_hh_f  = (const float*)d_in[6];
  const float* b_f     = (const float*)d_in[7];
  const float* W_ih_b  = (const float*)d_in[8];
  const float* W_hh_b  = (const float*)d_in[9];
  const float* b_b     = (const float*)d_in[10];
  const float* feat    = (const float*)d_in[11];
  const float* upd_W   = (const float*)d_in[12];
  const float* upd_b   = (const float*)d_in[13];
  const float* mapemb  = (const float*)d_in[14];
  const float* conv_w  = (const float*)d_in[15];
  float* out = (float*)d_out;  // 2 x f32 (loss, acc)
  char* ws = (char*)d_ws;
  size_t off = 0;
  auto alloc = [&](size_t bytes) {
    void* p = ws + off; off += (bytes + 255) & ~(size_t)255; return p;
  };
  f16*   x16    = (f16*)alloc(33554432);   // [t*128+b][512] f16; dead post-LSTM
  f16*   hid    = (f16*)alloc(67108864);   // hidden f16 [b][t][1024]
  f16*   hgb    = (f16*)alloc(524288);     // h state [d][parity][128][512]
  int*   bar    = (int*)alloc(1024);       // flags [d][bh][ug] (monotone)
  float* la     = (float*)alloc(256);      // loss/acc f32 accum
  float* ctrlA  = (float*)alloc(524288);
  float* ctrlB  = (float*)alloc(524288);
  float* msgs   = (float*)alloc(1572864);  // 3 x [128][1024] f32
  f16*   cat    = (f16*)alloc(524288);     // [128][2048] f16
  f16*   l0b    = (f16*)alloc(4194304);    // [b*16+p][1024] f16
  f16*   l1b    = (f16*)alloc(4194304);
  f16*   l2b    = (f16*)alloc(4194304);
  // aliases into the x16 region (only used after the LSTM):
  f16*   patch  = x16;                      // [2048][4096] f16, 16 MB
  f16*   w416   = x16 + 8388608;            // [1024][4096] f16, 8 MB
  f16*   updW16 = x16 + 12582912;           // [1024][2048] f16, 4 MB
  if (ws_size < off) {                      // ~112 MB needed
    fail_kernel<<<1, 64, 0, stream>>>(out, (int)(off >> 20));
    return;
  }

  init_kernel<<<512, 256, 0, stream>>>(hgb, bar, la, ctrlA, feat);
  embed_kernel<<<32768, 256, 0, stream>>>(Xs, emb, x16);
  {
    void* args[] = {(void*)&x16, (void*)&W_ih_f, (void*)&W_ih_b,
                    (void*)&W_hh_f, (void*)&W_hh_b, (void*)&b_f, (void*)&b_b,
                    (void*)&hgb, (void*)&hid, (void*)&bar};
    hipLaunchCooperativeKernel((void*)lstm_kernel, dim3(256), dim3(256), args, 0, stream);
  }
  prep2_kernel<<<16384, 256, 0, stream>>>(upd_W, conv_w, updW16, w416);
  // landmark path
  l0_kernel<<<2048, 256, 0, stream>>>(lm, mapemb, l0b);
  patch_kernel<<<2048, 256, 0, stream>>>(l0b, patch);
  gemm_kernel<<<dim3(16, 8), 256, 0, stream>>>(patch, w416, nullptr, l1b,
                                               2048, 1024, 4096, 1);
  patch_kernel<<<2048, 256, 0, stream>>>(l1b, patch);
  gemm_kernel<<<dim3(16, 8), 256, 0, stream>>>(patch, w416, nullptr, l2b,
                                               2048, 1024, 4096, 1);
  // attention x3 (controller ping-pong); ctrl' = cat @ upd_W^T + upd_b (f32)
  att_kernel<<<128, 256, 0, stream>>>(hid, ctrlA, seqmask, msgs, cat);
  gemm_kernel<<<dim3(1, 8), 256, 0, stream>>>(cat, updW16, upd_b, ctrlB,
                                              128, 1024, 2048, 0);
  att_kernel<<<128, 256, 0, stream>>>(hid, ctrlB, seqmask, msgs + 131072, cat);
  gemm_kernel<<<dim3(1, 8), 256, 0, stream>>>(cat, updW16, upd_b, ctrlA,
                                              128, 1024, 2048, 0);
  att_kernel<<<128, 256, 0, stream>>>(hid, ctrlA, seqmask, msgs + 262144, nullptr);
  logits_kernel<<<128, 256, 0, stream>>>(l0b, l1b, l2b, msgs, ys, la);
  finalize_kernel<<<1, 64, 0, stream>>>(la, out);
}

// Round 5
// 1750.665 us; speedup vs baseline: 6.0115x; 1.5779x over previous
//
#include <hip/hip_runtime.h>

// ---------------------------------------------------------------------------
// LocationPredictor: embed -> biLSTM -> attention x3 -> masked conv x2 -> loss
// B=128 T=256 E=512 HSZ=1024 HD=512 VOCAB=2048 LVOCAB=11 K=6 STEPS=3
// Output d_out = 2 x float32 (loss, acc). Workspace ~112 MB.
// LSTM: cooperative persistent kernel; block = (dir, 16 batch rows, 32 units),
// wave-specialized weights in registers; h exchanged via system-coherent
// stores + MALL-reading staged loads; 16-wide flag sub-barriers; x-tile
// double-buffered in LDS and prefetched during the barrier wait.
// ---------------------------------------------------------------------------

typedef _Float16 f16;
typedef __attribute__((ext_vector_type(8))) _Float16 f16x8;
typedef __attribute__((ext_vector_type(4))) float f32x4;

#define DEV __device__ __forceinline__

DEV void gload_lds16(const void* g, void* lds) {
  // async global->LDS, 16B per lane, LDS dst = uniform base + lane*16 (cached)
  __builtin_amdgcn_global_load_lds(
      (const __attribute__((address_space(1))) unsigned*)g,
      (__attribute__((address_space(3))) unsigned*)lds, 16, 0, 0);
}
DEV void gload_lds16c(const void* g, void* lds) {
  // coherent variant: aux = SC0|SC1 -> bypass L1/L2, read coherence point
  __builtin_amdgcn_global_load_lds(
      (const __attribute__((address_space(1))) unsigned*)g,
      (__attribute__((address_space(3))) unsigned*)lds, 16, 0, 17);
}
DEV float sigm(float x) { return 1.0f / (1.0f + __expf(-x)); }
DEV float tanh_(float x) { return 1.0f - 2.0f / (__expf(2.0f * x) + 1.0f); }
DEV unsigned pck(float a, float b) {
  union { unsigned u; f16 h[2]; } c; c.h[0] = (f16)a; c.h[1] = (f16)b; return c.u;
}

// ---------------------------------------------------------------------------
// Generic f16 GEMM: C[M][N] = A[M][K] * B[N][K]^T (+bias[n]); tiles 128x128,
// BK=32, global_load_lds staging, mfma_f32_16x16x32_f16. cmode 1->f16, 0->f32.
// ---------------------------------------------------------------------------
__global__ __launch_bounds__(256) void gemm_kernel(
    const f16* __restrict__ A, const f16* __restrict__ B,
    const float* __restrict__ bias, void* __restrict__ Cp,
    int M, int N, int K, int cmode) {
  __shared__ f16 As[128 * 32];
  __shared__ f16 Bs[128 * 32];
  const int tid = threadIdx.x;
  const int w = tid >> 6, l = tid & 63;
  const int m0 = blockIdx.x * 128, n0 = blockIdx.y * 128;
  const int wm = (w & 1) * 64, wn = (w >> 1) * 64;
  const int lr = l & 15, lq = l >> 4;
  const int srow = w * 32 + (l >> 2);
  const int kc8 = (l & 3) * 8;
  f32x4 acc[4][4];
#pragma unroll
  for (int i = 0; i < 4; ++i)
#pragma unroll
    for (int j = 0; j < 4; ++j) acc[i][j] = (f32x4){0.f, 0.f, 0.f, 0.f};

  for (int kt = 0; kt < K; kt += 32) {
    __syncthreads();
#pragma unroll
    for (int i = 0; i < 2; ++i) {
      gload_lds16(A + (long)(m0 + srow + i * 16) * K + kt + kc8,
                  &As[(w * 32 + i * 16) * 32]);
      gload_lds16(B + (long)(n0 + srow + i * 16) * K + kt + kc8,
                  &Bs[(w * 32 + i * 16) * 32]);
    }
    __syncthreads();
    f16x8 af[4], bf[4];
#pragma unroll
    for (int mi = 0; mi < 4; ++mi)
      af[mi] = *(const f16x8*)&As[(wm + mi * 16 + lr) * 32 + lq * 8];
#pragma unroll
    for (int ni = 0; ni < 4; ++ni)
      bf[ni] = *(const f16x8*)&Bs[(wn + ni * 16 + lr) * 32 + lq * 8];
#pragma unroll
    for (int mi = 0; mi < 4; ++mi)
#pragma unroll
      for (int ni = 0; ni < 4; ++ni)
        acc[mi][ni] =
            __builtin_amdgcn_mfma_f32_16x16x32_f16(af[mi], bf[ni], acc[mi][ni], 0, 0, 0);
  }
#pragma unroll
  for (int mi = 0; mi < 4; ++mi)
#pragma unroll
    for (int ni = 0; ni < 4; ++ni)
#pragma unroll
      for (int r = 0; r < 4; ++r) {
        const int m = m0 + wm + mi * 16 + lq * 4 + r;  // C row = quad*4+reg
        const int n = n0 + wn + ni * 16 + lr;          // C col = lane&15
        float v = acc[mi][ni][r];
        if (bias) v += bias[n];
        if (cmode) ((f16*)Cp)[(long)m * N + n] = (f16)v;
        else       ((float*)Cp)[(long)m * N + n] = v;
      }
}

// ---------------------------------------------------------------------------
// Cooperative biLSTM. 256 blocks x 256 threads (1 block/CU).
// blk: d=blk>>7; r=blk&127: ug=r&15 (32 units), bg=r>>4 (16 batch rows).
// Wave w owns units u0=ug*32+w*8 .. +8 (W_ih/W_hh B-fragments in registers).
// Per step: [xs holds x@t] poll 16 flags -> barrier -> x-MFMA -> stage h@s
// (coherent) -> barrier -> h-MFMA -> wave-local gate transpose -> eltwise ->
// coherent h store -> drain -> barrier -> flag=s+1 -> prefetch x@t+1 -> loop.
// hg: [d][parity][128][512] f16. hidden: [b][t][1024] f16 (fwd | bwd).
// flags: bar[((d*8+bg)*16)+ug], monotone step counters.
// ---------------------------------------------------------------------------
__global__ __launch_bounds__(256, 1) void lstm_kernel(
    const f16* __restrict__ x16,
    const float* __restrict__ Wih_f, const float* __restrict__ Wih_b,
    const float* __restrict__ Whh_f, const float* __restrict__ Whh_b,
    const float* __restrict__ b_f, const float* __restrict__ b_b,
    f16* __restrict__ hg, f16* __restrict__ hidden, int* __restrict__ bar) {
  __shared__ f16 hs[16 * 16 * 32];      // 16 KB  h stage [kt][m16][kk32]
  __shared__ f16 xs[16 * 16 * 32];      // 16 KB  x stage (double-duty prefetch)
  __shared__ float gb[4][16][32];       // 8 KB   per-wave gate transpose
  const int blk = blockIdx.x, tid = threadIdx.x;
  const int d = blk >> 7, rr = blk & 127;
  const int ug = rr & 15, bg = rr >> 4;
  const int b0 = bg * 16;
  const int w = tid >> 6, l = tid & 63;
  const int lr = l & 15, lq = l >> 4;
  const int u0 = ug * 32 + w * 8;       // wave-owned unit base
  const float* const Wih = d ? Wih_b : Wih_f;
  const float* const Whh = d ? Whh_b : Whh_f;
  const float* const bb = d ? b_b : b_f;

  // --- one-time: weights -> registers as MFMA B-fragments (f32 -> f16) ---
  f16x8 wih[16][2], whh[16][2];
#pragma unroll
  for (int kt = 0; kt < 16; ++kt)
#pragma unroll
    for (int nt = 0; nt < 2; ++nt) {
      const int n = nt * 16 + lr;                       // gate row within 32
      const long row = (long)((n >> 3) * 512 + u0 + (n & 7));
      const float* pi = Wih + row * 512 + kt * 32 + lq * 8;
      const float* ph = Whh + row * 512 + kt * 32 + lq * 8;
      f16x8 va, vb;
#pragma unroll
      for (int j = 0; j < 8; ++j) { va[j] = (f16)pi[j]; vb[j] = (f16)ph[j]; }
      wih[kt][nt] = va; whh[kt][nt] = vb;
    }
  const int bl = l >> 2, jp = (l & 3) * 2;   // eltwise: row bl, units jp,jp+1
  const int b_my = b0 + bl;
  const float bi0 = bb[u0 + jp],        bi1 = bb[u0 + jp + 1];
  const float bF0 = bb[512 + u0 + jp],  bF1 = bb[512 + u0 + jp + 1];
  const float bg0 = bb[1024 + u0 + jp], bg1 = bb[1024 + u0 + jp + 1];
  const float bo0 = bb[1536 + u0 + jp], bo1 = bb[1536 + u0 + jp + 1];
  float c0 = 0.f, c1 = 0.f;
  f16* const hbase = hg + (d * 2) * 65536;
  int* const flagbase = &bar[((d << 3) + bg) << 4];

  // stage 16 rows x 512 cols f16: wave w does kt = w*4..w*4+4, one instr each
#define STAGE16(DST, SRCP, LOADER)                                            \
  {                                                                           \
    const f16* _s = (SRCP);                                                   \
    _Pragma("unroll") for (int k4 = 0; k4 < 4; ++k4) {                        \
      const int kt = w * 4 + k4;                                              \
      LOADER(_s + (long)(l >> 2) * 512 + kt * 32 + (l & 3) * 8,               \
             &DST[(kt * 16) * 32]);                                           \
    }                                                                         \
  }

  // initial x stage for s=0
  STAGE16(xs, x16 + ((long)(d ? 255 : 0) * 128 + b0) * 512, gload_lds16);

  for (int s = 0; s < 256; ++s) {
    const int t = d ? (255 - s) : s;
    const f16* const hrd = hbase + (s & 1) * 65536;
    f16* const hwr = hbase + ((s + 1) & 1) * 65536;
    // 1. wait for h@s from the 16 writer blocks of my (d,bg)
    if (w == 0 && l < 16) {
      while (__hip_atomic_load(&flagbase[l], __ATOMIC_RELAXED,
                               __HIP_MEMORY_SCOPE_SYSTEM) < s)
        __builtin_amdgcn_s_sleep(1);
    }
    __syncthreads();  // also drains each wave's x prefetch (auto vmcnt)
    // 2. x-MFMA from prefetched xs
    f32x4 a0 = (f32x4){0.f, 0.f, 0.f, 0.f}, a1 = (f32x4){0.f, 0.f, 0.f, 0.f};
#pragma unroll
    for (int kt = 0; kt < 16; ++kt) {
      const f16x8 av = *(const f16x8*)&xs[(kt * 16 + lr) * 32 + lq * 8];
      a0 = __builtin_amdgcn_mfma_f32_16x16x32_f16(av, wih[kt][0], a0, 0, 0, 0);
      a1 = __builtin_amdgcn_mfma_f32_16x16x32_f16(av, wih[kt][1], a1, 0, 0, 0);
    }
    __builtin_amdgcn_sched_barrier(0);  // keep xs reads before h-stage issue
    // 3. stage h@s (coherent, from MALL)
    STAGE16(hs, hrd + (long)b0 * 512, gload_lds16c);
    __syncthreads();  // vmcnt0: hs complete for all waves
    // 4. h-MFMA
#pragma unroll
    for (int kt = 0; kt < 16; ++kt) {
      const f16x8 av = *(const f16x8*)&hs[(kt * 16 + lr) * 32 + lq * 8];
      a0 = __builtin_amdgcn_mfma_f32_16x16x32_f16(av, whh[kt][0], a0, 0, 0, 0);
      a1 = __builtin_amdgcn_mfma_f32_16x16x32_f16(av, whh[kt][1], a1, 0, 0, 0);
    }
    // 5. wave-local gate transpose via LDS
#pragma unroll
    for (int r = 0; r < 4; ++r) {
      gb[w][lq * 4 + r][lr] = a0[r];
      gb[w][lq * 4 + r][16 + lr] = a1[r];
    }
    __builtin_amdgcn_s_waitcnt(0xC07F);  // lgkmcnt(0): LDS writes visible
    {
      const float* const gr = &gb[w][bl][0];
      float gi = gr[jp] + bi0, gf = gr[8 + jp] + bF0;
      float gg = gr[16 + jp] + bg0, go = gr[24 + jp] + bo0;
      c0 = sigm(gf) * c0 + sigm(gi) * tanh_(gg);
      const float h0 = sigm(go) * tanh_(c0);
      gi = gr[jp + 1] + bi1; gf = gr[8 + jp + 1] + bF1;
      gg = gr[16 + jp + 1] + bg1; go = gr[24 + jp + 1] + bo1;
      c1 = sigm(gf) * c1 + sigm(gi) * tanh_(gg);
      const float h1 = sigm(go) * tanh_(c1);
      const unsigned hp = pck(h0, h1);
      // h exchange: write-through to the coherence point
      __hip_atomic_store((unsigned*)&hwr[(b_my << 9) + u0 + jp], hp,
                         __ATOMIC_RELAXED, __HIP_MEMORY_SCOPE_SYSTEM);
      *(unsigned*)&hidden[((long)b_my * 256 + t) * 1024 + (d << 9) + u0 + jp] = hp;
    }
    // 6. drain stores, block-wide complete, publish flag
    __builtin_amdgcn_s_waitcnt(0);
    __syncthreads();
    if (tid == 0)
      __hip_atomic_store(&flagbase[ug], s + 1, __ATOMIC_RELAXED,
                         __HIP_MEMORY_SCOPE_SYSTEM);
    // 7. prefetch x@t+1 during the (next) barrier wait
    if (s < 255) {
      const int tn = d ? (254 - s) : (s + 1);
      STAGE16(xs, x16 + ((long)tn * 128 + b0) * 512, gload_lds16);
    }
  }
#undef STAGE16
}

// ---------------------------------------------------------------------------
// Attention: score = hidden . ctrl, softmax over T, msg = att . hidden.
// One block per batch row. Writes msg (f32) and optionally cat=[msg||ctrl] f16.
// ---------------------------------------------------------------------------
__global__ __launch_bounds__(256) void att_kernel(
    const f16* __restrict__ hidden, const float* __restrict__ ctrl,
    const float* __restrict__ seq_mask, float* __restrict__ msg_out,
    f16* __restrict__ cat) {
  __shared__ float sc[256];
  __shared__ float red[4];
  __shared__ float ctl[1024];
  const int b = blockIdx.x, tid = threadIdx.x;
  const int w = tid >> 6, l = tid & 63;
  for (int i = tid; i < 1024; i += 256) ctl[i] = ctrl[b * 1024 + i];
  __syncthreads();
  float cl[16];
#pragma unroll
  for (int j = 0; j < 16; ++j) cl[j] = ctl[l + 64 * j];
  const f16* hb = hidden + (long)b * 262144;
  for (int t = w * 64; t < w * 64 + 64; ++t) {
    float s = 0.f;
#pragma unroll
    for (int j = 0; j < 16; ++j) s += (float)hb[t * 1024 + l + 64 * j] * cl[j];
#pragma unroll
    for (int off = 32; off; off >>= 1) s += __shfl_xor(s, off);
    if (l == 0) sc[t] = s;
  }
  __syncthreads();
  const float v = sc[tid] - 1e30f * (1.0f - seq_mask[b * 256 + tid]);
  float m = v;
#pragma unroll
  for (int off = 32; off; off >>= 1) m = fmaxf(m, __shfl_xor(m, off));
  if (l == 0) red[w] = m;
  __syncthreads();
  const float M = fmaxf(fmaxf(red[0], red[1]), fmaxf(red[2], red[3]));
  const float e = __expf(v - M);
  float ss = e;
#pragma unroll
  for (int off = 32; off; off >>= 1) ss += __shfl_xor(ss, off);
  __syncthreads();
  if (l == 0) red[w] = ss;
  __syncthreads();
  const float S = red[0] + red[1] + red[2] + red[3];
  sc[tid] = e / S;
  __syncthreads();
  const int hc = tid * 4;
  float a0 = 0.f, a1 = 0.f, a2 = 0.f, a3 = 0.f;
  for (int t = 0; t < 256; ++t) {
    const float at = sc[t];
    union { uint2 u; f16 h[4]; } q;
    q.u = *(const uint2*)&hb[t * 1024 + hc];
    a0 += at * (float)q.h[0]; a1 += at * (float)q.h[1];
    a2 += at * (float)q.h[2]; a3 += at * (float)q.h[3];
  }
  float* mo = msg_out + b * 1024 + hc;
  mo[0] = a0; mo[1] = a1; mo[2] = a2; mo[3] = a3;
  if (cat) {
    f16* cm = cat + (long)b * 2048 + hc;
    cm[0] = (f16)a0; cm[1] = (f16)a1; cm[2] = (f16)a2; cm[3] = (f16)a3;
    f16* cc = cat + (long)b * 2048 + 1024 + hc;
    cc[0] = (f16)ctl[hc]; cc[1] = (f16)ctl[hc + 1];
    cc[2] = (f16)ctl[hc + 2]; cc[3] = (f16)ctl[hc + 3];
  }
}

// l0[b][p][h] = sum_k map_emb[landmarks[b,p,k]][h]  (f16 out)
__global__ __launch_bounds__(256) void l0_kernel(
    const int* __restrict__ lm, const float* __restrict__ me, f16* __restrict__ l0) {
  const int bp = blockIdx.x, tid = threadIdx.x;
  const int h = tid * 4;
  int id[6];
#pragma unroll
  for (int k = 0; k < 6; ++k) id[k] = lm[bp * 6 + k];
  float a0 = 0.f, a1 = 0.f, a2 = 0.f, a3 = 0.f;
#pragma unroll
  for (int k = 0; k < 6; ++k) {
    const float* r = me + id[k] * 1024 + h;
    a0 += r[0]; a1 += r[1]; a2 += r[2]; a3 += r[3];
  }
  union { uint2 u; f16 hh[4]; } pk;
  pk.hh[0] = (f16)a0; pk.hh[1] = (f16)a1; pk.hh[2] = (f16)a2; pk.hh[3] = (f16)a3;
  *(uint2*)&l0[(long)bp * 1024 + h] = pk.u;
}

// patch[(b*16+p)][i*4+tap] = src[b][nbr(p,tap)][i], taps = up,left,right,down
__global__ __launch_bounds__(256) void patch_kernel(
    const f16* __restrict__ src, f16* __restrict__ patch) {
  const int bp = blockIdx.x, tid = threadIdx.x;
  const int b = bp >> 4, p = bp & 15, y = p >> 2, x = p & 3;
  const int base = b * 16;
  f16* pr = patch + (long)bp * 4096;
  for (int i = tid; i < 1024; i += 256) {
    union { uint2 u; f16 h[4]; } pk;
    pk.h[0] = (y > 0) ? src[(long)(base + p - 4) * 1024 + i] : (f16)0.f;
    pk.h[1] = (x > 0) ? src[(long)(base + p - 1) * 1024 + i] : (f16)0.f;
    pk.h[2] = (x < 3) ? src[(long)(base + p + 1) * 1024 + i] : (f16)0.f;
    pk.h[3] = (y < 3) ? src[(long)(base + p + 4) * 1024 + i] : (f16)0.f;
    *(uint2*)&pr[i * 4] = pk.u;
  }
}

// logits -> softmax -> log_softmax(prob) -> loss/acc (atomicAdd into la[2] f32)
__global__ __launch_bounds__(256) void logits_kernel(
    const f16* __restrict__ l0, const f16* __restrict__ l1, const f16* __restrict__ l2,
    const float* __restrict__ msgs, const int* __restrict__ ys, float* __restrict__ la) {
  __shared__ float lg[16];
  const int b = blockIdx.x, tid = threadIdx.x;
  const int p = tid >> 4, q = tid & 15;
  const float* m0 = msgs + b * 1024;
  const float* m1 = msgs + 131072 + b * 1024;
  const float* m2 = msgs + 262144 + b * 1024;
  const long row = (long)(b * 16 + p) * 1024;
  float part = 0.f;
  for (int i = 0; i < 64; ++i) {
    const int h = q + 16 * i;
    part += (float)l0[row + h] * m0[h] + (float)l1[row + h] * m1[h] +
            (float)l2[row + h] * m2[h];
  }
#pragma unroll
  for (int off = 8; off; off >>= 1) part += __shfl_xor(part, off, 16);
  if (q == 0) lg[p] = part;
  __syncthreads();
  if (tid == 0) {
    float mx = lg[0];
    for (int i = 1; i < 16; ++i) mx = fmaxf(mx, lg[i]);
    float pr[16]; float s = 0.f;
    for (int i = 0; i < 16; ++i) { pr[i] = __expf(lg[i] - mx); s += pr[i]; }
    for (int i = 0; i < 16; ++i) pr[i] /= s;
    float mx2 = pr[0];
    for (int i = 1; i < 16; ++i) mx2 = fmaxf(mx2, pr[i]);
    float s2 = 0.f;
    for (int i = 0; i < 16; ++i) s2 += __expf(pr[i] - mx2);
    const float lse = mx2 + __logf(s2);
    const int y = ys[b * 2] * 4 + ys[b * 2 + 1];
    const float logp = pr[y] - lse;
    int am = 0; float bv = pr[0];
    for (int i = 1; i < 16; ++i) if (pr[i] > bv) { bv = pr[i]; am = i; }
    atomicAdd(&la[0], -logp * (1.0f / 128.0f));
    atomicAdd(&la[1], (am == y) ? (1.0f / 128.0f) : 0.0f);
  }
}

// d_out is 2 x FLOAT32 (loss, acc)
__global__ void finalize_kernel(const float* __restrict__ la,
                                float* __restrict__ out) {
  if (threadIdx.x == 0) { out[0] = la[0]; out[1] = la[1]; }
}

// x16[t*128+b][e] = (f16) emb[Xs[b][t]][e]
__global__ __launch_bounds__(256) void embed_kernel(
    const int* __restrict__ Xs, const float* __restrict__ emb, f16* __restrict__ x16) {
  const int m = blockIdx.x, tid = threadIdx.x;
  const int t = m >> 7, b = m & 127;
  const int v = Xs[b * 256 + t];
  const int e = tid * 2;
  const float2 f = *(const float2*)&emb[(long)v * 512 + e];
  *(unsigned*)&x16[(long)m * 512 + e] = pck(f.x, f.y);
}

// post-LSTM weight prep (targets alias the dead x16 region):
// updW16 f16 [1024][2048]; w4 f16 [1024][4096] = cross taps (0,1),(1,0),(1,2),(2,1)
__global__ __launch_bounds__(256) void prep2_kernel(
    const float* __restrict__ upd_W, const float* __restrict__ conv_w,
    f16* __restrict__ updW16, f16* __restrict__ w4) {
  const int idx = blockIdx.x * 256 + threadIdx.x;  // 0..4194303
  if (idx < 2097152) updW16[idx] = (f16)upd_W[idx];
  const int o = idx >> 12, r = idx & 4095, i = r >> 2, tp = r & 3;
  w4[idx] = (f16)conv_w[(long)(o * 1024 + i) * 9 + 1 + 2 * tp];
}

// zero h state / flags / loss accum, init controller = broadcast(feat_ctrl)
__global__ __launch_bounds__(256) void init_kernel(
    f16* __restrict__ hg, int* __restrict__ bar, float* __restrict__ la,
    float* __restrict__ ctrlA, const float* __restrict__ feat) {
  const int idx = blockIdx.x * 256 + threadIdx.x;  // 0..131071
  ((unsigned*)hg)[idx] = 0u;
  ctrlA[idx] = feat[idx & 1023];
  if (idx < 256) bar[idx] = 0;
  if (idx < 2) la[idx] = 0.f;
}

__global__ void fail_kernel(float* out, int mb) {
  if (threadIdx.x == 0) { out[0] = 12344.0f; out[1] = (float)mb; }
}

// ---------------------------------------------------------------------------
extern "C" void kernel_launch(void* const* d_in, const int* in_sizes, int n_in,
                              void* d_out, int out_size, void* d_ws, size_t ws_size,
                              hipStream_t stream) {
  (void)in_sizes; (void)n_in; (void)out_size;
  const int*   Xs      = (const int*)d_in[0];
  const float* seqmask = (const float*)d_in[1];
  const int*   lm      = (const int*)d_in[2];
  const int*   ys      = (const int*)d_in[3];
  const float* emb     = (const float*)d_in[4];
  const float* W_ih_f  = (const float*)d_in[5];
  const float* W_hh_f  = (const float*)d_in[6];
  const float* b_f     = (const float*)d_in[7];
  const float* W_ih_b  = (const float*)d_in[8];
  const float* W_hh_b  = (const float*)d_in[9];
  const float* b_b     = (const float*)d_in[10];
  const float* feat    = (const float*)d_in[11];
  const float* upd_W   = (const float*)d_in[12];
  const float* upd_b   = (const float*)d_in[13];
  const float* mapemb  = (const float*)d_in[14];
  const float* conv_w  = (const float*)d_in[15];
  float* out = (float*)d_out;  // 2 x f32 (loss, acc)
  char* ws = (char*)d_ws;
  size_t off = 0;
  auto alloc = [&](size_t bytes) {
    void* p = ws + off; off += (bytes + 255) & ~(size_t)255; return p;
  };
  f16*   x16    = (f16*)alloc(33554432);   // [t*128+b][512] f16; dead post-LSTM
  f16*   hid    = (f16*)alloc(67108864);   // hidden f16 [b][t][1024]
  f16*   hgb    = (f16*)alloc(524288);     // h state [d][parity][128][512]
  int*   bar    = (int*)alloc(1024);       // flags [d][bg][ug] (monotone)
  float* la     = (float*)alloc(256);      // loss/acc f32 accum
  float* ctrlA  = (float*)alloc(524288);
  float* ctrlB  = (float*)alloc(524288);
  float* msgs   = (float*)alloc(1572864);  // 3 x [128][1024] f32
  f16*   cat    = (f16*)alloc(524288);     // [128][2048] f16
  f16*   l0b    = (f16*)alloc(4194304);    // [b*16+p][1024] f16
  f16*   l1b    = (f16*)alloc(4194304);
  f16*   l2b    = (f16*)alloc(4194304);
  // aliases into the x16 region (only used after the LSTM):
  f16*   patch  = x16;                      // [2048][4096] f16, 16 MB
  f16*   w416   = x16 + 8388608;            // [1024][4096] f16, 8 MB
  f16*   updW16 = x16 + 12582912;           // [1024][2048] f16, 4 MB
  if (ws_size < off) {                      // ~112 MB needed
    fail_kernel<<<1, 64, 0, stream>>>(out, (int)(off >> 20));
    return;
  }

  init_kernel<<<512, 256, 0, stream>>>(hgb, bar, la, ctrlA, feat);
  embed_kernel<<<32768, 256, 0, stream>>>(Xs, emb, x16);
  {
    void* args[] = {(void*)&x16, (void*)&W_ih_f, (void*)&W_ih_b,
                    (void*)&W_hh_f, (void*)&W_hh_b, (void*)&b_f, (void*)&b_b,
                    (void*)&hgb, (void*)&hid, (void*)&bar};
    hipLaunchCooperativeKernel((void*)lstm_kernel, dim3(256), dim3(256), args, 0, stream);
  }
  prep2_kernel<<<16384, 256, 0, stream>>>(upd_W, conv_w, updW16, w416);
  // landmark path
  l0_kernel<<<2048, 256, 0, stream>>>(lm, mapemb, l0b);
  patch_kernel<<<2048, 256, 0, stream>>>(l0b, patch);
  gemm_kernel<<<dim3(16, 8), 256, 0, stream>>>(patch, w416, nullptr, l1b,
                                               2048, 1024, 4096, 1);
  patch_kernel<<<2048, 256, 0, stream>>>(l1b, patch);
  gemm_kernel<<<dim3(16, 8), 256, 0, stream>>>(patch, w416, nullptr, l2b,
                                               2048, 1024, 4096, 1);
  // attention x3 (controller ping-pong); ctrl' = cat @ upd_W^T + upd_b (f32)
  att_kernel<<<128, 256, 0, stream>>>(hid, ctrlA, seqmask, msgs, cat);
  gemm_kernel<<<dim3(1, 8), 256, 0, stream>>>(cat, updW16, upd_b, ctrlB,
                                              128, 1024, 2048, 0);
  att_kernel<<<128, 256, 0, stream>>>(hid, ctrlB, seqmask, msgs + 131072, cat);
  gemm_kernel<<<dim3(1, 8), 256, 0, stream>>>(cat, updW16, upd_b, ctrlA,
                                              128, 1024, 2048, 0);
  att_kernel<<<128, 256, 0, stream>>>(hid, ctrlA, seqmask, msgs + 262144, nullptr);
  logits_kernel<<<128, 256, 0, stream>>>(l0b, l1b, l2b, msgs, ys, la);
  finalize_kernel<<<1, 64, 0, stream>>>(la, out);
}

// Round 8
// 1566.638 us; speedup vs baseline: 6.7176x; 1.1175x over previous
//
#include <hip/hip_runtime.h>

// ---------------------------------------------------------------------------
// LocationPredictor: embed -> biLSTM -> attention x3 -> masked conv x2 -> loss
// B=128 T=256 E=512 HSZ=1024 HD=512 VOCAB=2048 LVOCAB=11 K=6 STEPS=3
// Output d_out = 2 x float32 (loss, acc). Workspace ~112 MB.
// LSTM: cooperative persistent kernel; block = (dir, 16 batch rows, 32 units);
// h exchanged via system-coherent stores + MALL-reading staged loads (proven
// round-5 protocol; NO XCD fast path); 16-wide flag sub-barriers; x-MFMA,
// hidden[] store and x-prefetch pipelined into the step tail (xs ping-pong).
// ---------------------------------------------------------------------------

typedef _Float16 f16;
typedef __attribute__((ext_vector_type(8))) _Float16 f16x8;
typedef __attribute__((ext_vector_type(4))) float f32x4;

#define DEV __device__ __forceinline__

DEV void gload_lds16(const void* g, void* lds) {   // cached (L1+L2)
  __builtin_amdgcn_global_load_lds(
      (const __attribute__((address_space(1))) unsigned*)g,
      (__attribute__((address_space(3))) unsigned*)lds, 16, 0, 0);
}
DEV void gload_lds16c(const void* g, void* lds) {  // SC0|SC1: read MALL
  __builtin_amdgcn_global_load_lds(
      (const __attribute__((address_space(1))) unsigned*)g,
      (__attribute__((address_space(3))) unsigned*)lds, 16, 0, 17);
}
DEV float sigm(float x) { return 1.0f / (1.0f + __expf(-x)); }
DEV float tanh_(float x) { return 1.0f - 2.0f / (__expf(2.0f * x) + 1.0f); }
DEV unsigned pck(float a, float b) {
  union { unsigned u; f16 h[2]; } c; c.h[0] = (f16)a; c.h[1] = (f16)b; return c.u;
}

// ---------------------------------------------------------------------------
// Generic f16 GEMM: C[M][N] = A[M][K] * B[N][K]^T (+bias[n]); tiles 128x128,
// BK=32, global_load_lds staging, mfma_f32_16x16x32_f16. cmode 1->f16, 0->f32.
// ---------------------------------------------------------------------------
__global__ __launch_bounds__(256) void gemm_kernel(
    const f16* __restrict__ A, const f16* __restrict__ B,
    const float* __restrict__ bias, void* __restrict__ Cp,
    int M, int N, int K, int cmode) {
  __shared__ f16 As[128 * 32];
  __shared__ f16 Bs[128 * 32];
  const int tid = threadIdx.x;
  const int w = tid >> 6, l = tid & 63;
  const int m0 = blockIdx.x * 128, n0 = blockIdx.y * 128;
  const int wm = (w & 1) * 64, wn = (w >> 1) * 64;
  const int lr = l & 15, lq = l >> 4;
  const int srow = w * 32 + (l >> 2);
  const int kc8 = (l & 3) * 8;
  f32x4 acc[4][4];
#pragma unroll
  for (int i = 0; i < 4; ++i)
#pragma unroll
    for (int j = 0; j < 4; ++j) acc[i][j] = (f32x4){0.f, 0.f, 0.f, 0.f};

  for (int kt = 0; kt < K; kt += 32) {
    __syncthreads();
#pragma unroll
    for (int i = 0; i < 2; ++i) {
      gload_lds16(A + (long)(m0 + srow + i * 16) * K + kt + kc8,
                  &As[(w * 32 + i * 16) * 32]);
      gload_lds16(B + (long)(n0 + srow + i * 16) * K + kt + kc8,
                  &Bs[(w * 32 + i * 16) * 32]);
    }
    __syncthreads();
    f16x8 af[4], bf[4];
#pragma unroll
    for (int mi = 0; mi < 4; ++mi)
      af[mi] = *(const f16x8*)&As[(wm + mi * 16 + lr) * 32 + lq * 8];
#pragma unroll
    for (int ni = 0; ni < 4; ++ni)
      bf[ni] = *(const f16x8*)&Bs[(wn + ni * 16 + lr) * 32 + lq * 8];
#pragma unroll
    for (int mi = 0; mi < 4; ++mi)
#pragma unroll
      for (int ni = 0; ni < 4; ++ni)
        acc[mi][ni] =
            __builtin_amdgcn_mfma_f32_16x16x32_f16(af[mi], bf[ni], acc[mi][ni], 0, 0, 0);
  }
#pragma unroll
  for (int mi = 0; mi < 4; ++mi)
#pragma unroll
    for (int ni = 0; ni < 4; ++ni)
#pragma unroll
      for (int r = 0; r < 4; ++r) {
        const int m = m0 + wm + mi * 16 + lq * 4 + r;  // C row = quad*4+reg
        const int n = n0 + wn + ni * 16 + lr;          // C col = lane&15
        float v = acc[mi][ni][r];
        if (bias) v += bias[n];
        if (cmode) ((f16*)Cp)[(long)m * N + n] = (f16)v;
        else       ((float*)Cp)[(long)m * N + n] = v;
      }
}

// ---------------------------------------------------------------------------
// Cooperative biLSTM. 256 blocks x 256 threads (1 block/CU).
// blk: d=blk>>7; rr=blk&127: ug=rr&15 (32 units), bg=rr>>4 (16 batch rows).
// Wave w owns units u0=ug*32+w*8 .. +8 (W_ih/W_hh B-fragments in registers).
// Per step: poll 16 flags -> sync -> stage h@s (MALL) -> vmcnt+sync ->
// h-MFMA (on top of x contribution from previous tail) -> wave-local gate
// transpose -> eltwise -> system h store -> drain -> sync -> publish flag ->
// TAIL: hidden[] store, x-MFMA@t+1 (xs ping-pong), prefetch x@t+2.
// hg: [d][parity][128][512] f16. hidden: [b][t][1024] f16 (fwd | bwd).
// flags: bar[((d*8+bg)*16)+ug], monotone step counters (round-5 proven).
// ---------------------------------------------------------------------------
__global__ __launch_bounds__(256, 1) void lstm_kernel(
    const f16* __restrict__ x16,
    const float* __restrict__ Wih_f, const float* __restrict__ Wih_b,
    const float* __restrict__ Whh_f, const float* __restrict__ Whh_b,
    const float* __restrict__ b_f, const float* __restrict__ b_b,
    f16* __restrict__ hg, f16* __restrict__ hidden, int* __restrict__ bar) {
  __shared__ f16 hs[16 * 16 * 32];      // 16 KB h stage [kt][m16][kk32]
  __shared__ f16 xs[2][16 * 16 * 32];   // 32 KB x stage ping-pong
  __shared__ float gb[4][16][32];       // 8 KB  per-wave gate transpose
  const int blk = blockIdx.x, tid = threadIdx.x;
  const int d = blk >> 7, rr = blk & 127;
  const int ug = rr & 15, bg = rr >> 4;
  const int b0 = bg * 16;
  const int w = tid >> 6, l = tid & 63;
  const int lr = l & 15, lq = l >> 4;
  const int u0 = ug * 32 + w * 8;       // wave-owned unit base
  const float* const Wih = d ? Wih_b : Wih_f;
  const float* const Whh = d ? Whh_b : Whh_f;
  const float* const bb = d ? b_b : b_f;
  int* const flagbase = &bar[((d << 3) + bg) << 4];

  // --- one-time: weights -> registers as MFMA B-fragments (f32 -> f16) ---
  f16x8 wih[16][2], whh[16][2];
#pragma unroll
  for (int kt = 0; kt < 16; ++kt)
#pragma unroll
    for (int nt = 0; nt < 2; ++nt) {
      const int n = nt * 16 + lr;                       // gate row within 32
      const long row = (long)((n >> 3) * 512 + u0 + (n & 7));
      const float* pi = Wih + row * 512 + kt * 32 + lq * 8;
      const float* ph = Whh + row * 512 + kt * 32 + lq * 8;
      f16x8 va, vb;
#pragma unroll
      for (int j = 0; j < 8; ++j) { va[j] = (f16)pi[j]; vb[j] = (f16)ph[j]; }
      wih[kt][nt] = va; whh[kt][nt] = vb;
    }
  const int bl = l >> 2, jp = (l & 3) * 2;   // eltwise: row bl, units jp,jp+1
  const int b_my = b0 + bl;
  const float bi0 = bb[u0 + jp],        bi1 = bb[u0 + jp + 1];
  const float bF0 = bb[512 + u0 + jp],  bF1 = bb[512 + u0 + jp + 1];
  const float bg0 = bb[1024 + u0 + jp], bg1 = bb[1024 + u0 + jp + 1];
  const float bo0 = bb[1536 + u0 + jp], bo1 = bb[1536 + u0 + jp + 1];
  float c0 = 0.f, c1 = 0.f;
  f16* const hbase = hg + (d * 2) * 65536;

#define STAGE16(DST, SRCP, LOADER)                                            \
  {                                                                           \
    const f16* _s = (SRCP);                                                   \
    _Pragma("unroll") for (int k4 = 0; k4 < 4; ++k4) {                        \
      const int kt = w * 4 + k4;                                              \
      LOADER(_s + (long)(l >> 2) * 512 + kt * 32 + (l & 3) * 8,               \
             &DST[(kt * 16) * 32]);                                           \
    }                                                                         \
  }

  // pre-loop: stage x@t0 -> xs[0]; x-MFMA@t0; prefetch x@t1 -> xs[1]
  STAGE16(xs[0], x16 + ((long)(d ? 255 : 0) * 128 + b0) * 512, gload_lds16);
  __builtin_amdgcn_s_waitcnt(0x0F70);  // vmcnt(0)
  __syncthreads();
  f32x4 a0 = (f32x4){0.f, 0.f, 0.f, 0.f}, a1 = (f32x4){0.f, 0.f, 0.f, 0.f};
#pragma unroll
  for (int kt = 0; kt < 16; ++kt) {
    const f16x8 av = *(const f16x8*)&xs[0][(kt * 16 + lr) * 32 + lq * 8];
    a0 = __builtin_amdgcn_mfma_f32_16x16x32_f16(av, wih[kt][0], a0, 0, 0, 0);
    a1 = __builtin_amdgcn_mfma_f32_16x16x32_f16(av, wih[kt][1], a1, 0, 0, 0);
  }
  STAGE16(xs[1], x16 + ((long)(d ? 254 : 1) * 128 + b0) * 512, gload_lds16);

  for (int s = 0; s < 256; ++s) {
    const int t = d ? (255 - s) : s;
    const f16* const hrd = hbase + (s & 1) * 65536;
    f16* const hwr = hbase + ((s + 1) & 1) * 65536;
    // 1. wait for h@s from the 16 writer blocks of my (d,bg)
    if (w == 0 && l < 16) {
      while (__hip_atomic_load(&flagbase[l], __ATOMIC_RELAXED,
                               __HIP_MEMORY_SCOPE_SYSTEM) < s)
        __builtin_amdgcn_s_sleep(1);
    }
    __syncthreads();
    // 2. stage h@s (coherent, from MALL)
    STAGE16(hs, hrd + (long)b0 * 512, gload_lds16c);
    __builtin_amdgcn_s_waitcnt(0x0F70);  // vmcnt(0): hs + last x prefetch
    __syncthreads();                     // all waves' chunks landed
    // 3. h-MFMA on top of the x contribution computed in the previous tail
#pragma unroll
    for (int kt = 0; kt < 16; ++kt) {
      const f16x8 av = *(const f16x8*)&hs[(kt * 16 + lr) * 32 + lq * 8];
      a0 = __builtin_amdgcn_mfma_f32_16x16x32_f16(av, whh[kt][0], a0, 0, 0, 0);
      a1 = __builtin_amdgcn_mfma_f32_16x16x32_f16(av, whh[kt][1], a1, 0, 0, 0);
    }
    // 4. wave-local gate transpose + eltwise
#pragma unroll
    for (int r = 0; r < 4; ++r) {
      gb[w][lq * 4 + r][lr] = a0[r];
      gb[w][lq * 4 + r][16 + lr] = a1[r];
    }
    __builtin_amdgcn_s_waitcnt(0xC07F);  // lgkmcnt(0): my LDS writes visible
    unsigned hp;
    {
      const float* const gr = &gb[w][bl][0];
      float gi = gr[jp] + bi0, gf = gr[8 + jp] + bF0;
      float gg = gr[16 + jp] + bg0, go = gr[24 + jp] + bo0;
      c0 = sigm(gf) * c0 + sigm(gi) * tanh_(gg);
      const float h0 = sigm(go) * tanh_(c0);
      gi = gr[jp + 1] + bi1; gf = gr[8 + jp + 1] + bF1;
      gg = gr[16 + jp + 1] + bg1; go = gr[24 + jp + 1] + bo1;
      c1 = sigm(gf) * c1 + sigm(gi) * tanh_(gg);
      const float h1 = sigm(go) * tanh_(c1);
      hp = pck(h0, h1);
      // h exchange: write-through to the coherence point (round-5 proven)
      __hip_atomic_store((unsigned*)&hwr[(b_my << 9) + u0 + jp], hp,
                         __ATOMIC_RELAXED, __HIP_MEMORY_SCOPE_SYSTEM);
    }
    // 5. drain h stores, block-complete, publish flag
    __builtin_amdgcn_s_waitcnt(0x0F70);  // vmcnt(0)
    __syncthreads();
    if (tid == 0)
      __hip_atomic_store(&flagbase[ug], s + 1, __ATOMIC_RELAXED,
                         __HIP_MEMORY_SCOPE_SYSTEM);
    // 6. tail (hidden store, next x-MFMA, next prefetch) behind the publish
    *(unsigned*)&hidden[((long)b_my * 256 + t) * 1024 + (d << 9) + u0 + jp] = hp;
    if (s < 255) {
      a0 = (f32x4){0.f, 0.f, 0.f, 0.f}; a1 = (f32x4){0.f, 0.f, 0.f, 0.f};
      const f16* const xr = &xs[(s + 1) & 1][0];
#pragma unroll
      for (int kt = 0; kt < 16; ++kt) {
        const f16x8 av = *(const f16x8*)&xr[(kt * 16 + lr) * 32 + lq * 8];
        a0 = __builtin_amdgcn_mfma_f32_16x16x32_f16(av, wih[kt][0], a0, 0, 0, 0);
        a1 = __builtin_amdgcn_mfma_f32_16x16x32_f16(av, wih[kt][1], a1, 0, 0, 0);
      }
      if (s < 254) {
        const int tp = d ? (253 - s) : (s + 2);
        STAGE16(xs[s & 1], x16 + ((long)tp * 128 + b0) * 512, gload_lds16);
      }
    }
  }
#undef STAGE16
}

// ---------------------------------------------------------------------------
// Attention: score = hidden . ctrl, softmax over T, msg = att . hidden.
// One block per batch row. Writes msg (f32) and optionally cat=[msg||ctrl] f16.
// ---------------------------------------------------------------------------
__global__ __launch_bounds__(256) void att_kernel(
    const f16* __restrict__ hidden, const float* __restrict__ ctrl,
    const float* __restrict__ seq_mask, float* __restrict__ msg_out,
    f16* __restrict__ cat) {
  __shared__ float sc[256];
  __shared__ float red[4];
  __shared__ float ctl[1024];
  const int b = blockIdx.x, tid = threadIdx.x;
  const int w = tid >> 6, l = tid & 63;
  for (int i = tid; i < 1024; i += 256) ctl[i] = ctrl[b * 1024 + i];
  __syncthreads();
  float cl[16];
#pragma unroll
  for (int j = 0; j < 16; ++j) cl[j] = ctl[l + 64 * j];
  const f16* hb = hidden + (long)b * 262144;
  for (int t = w * 64; t < w * 64 + 64; ++t) {
    float s = 0.f;
#pragma unroll
    for (int j = 0; j < 16; ++j) s += (float)hb[t * 1024 + l + 64 * j] * cl[j];
#pragma unroll
    for (int off = 32; off; off >>= 1) s += __shfl_xor(s, off);
    if (l == 0) sc[t] = s;
  }
  __syncthreads();
  const float v = sc[tid] - 1e30f * (1.0f - seq_mask[b * 256 + tid]);
  float m = v;
#pragma unroll
  for (int off = 32; off; off >>= 1) m = fmaxf(m, __shfl_xor(m, off));
  if (l == 0) red[w] = m;
  __syncthreads();
  const float M = fmaxf(fmaxf(red[0], red[1]), fmaxf(red[2], red[3]));
  const float e = __expf(v - M);
  float ss = e;
#pragma unroll
  for (int off = 32; off; off >>= 1) ss += __shfl_xor(ss, off);
  __syncthreads();
  if (l == 0) red[w] = ss;
  __syncthreads();
  const float S = red[0] + red[1] + red[2] + red[3];
  sc[tid] = e / S;
  __syncthreads();
  const int hc = tid * 4;
  float a0 = 0.f, a1 = 0.f, a2 = 0.f, a3 = 0.f;
  for (int t = 0; t < 256; ++t) {
    const float at = sc[t];
    union { uint2 u; f16 h[4]; } q;
    q.u = *(const uint2*)&hb[t * 1024 + hc];
    a0 += at * (float)q.h[0]; a1 += at * (float)q.h[1];
    a2 += at * (float)q.h[2]; a3 += at * (float)q.h[3];
  }
  float* mo = msg_out + b * 1024 + hc;
  mo[0] = a0; mo[1] = a1; mo[2] = a2; mo[3] = a3;
  if (cat) {
    f16* cm = cat + (long)b * 2048 + hc;
    cm[0] = (f16)a0; cm[1] = (f16)a1; cm[2] = (f16)a2; cm[3] = (f16)a3;
    f16* cc = cat + (long)b * 2048 + 1024 + hc;
    cc[0] = (f16)ctl[hc]; cc[1] = (f16)ctl[hc + 1];
    cc[2] = (f16)ctl[hc + 2]; cc[3] = (f16)ctl[hc + 3];
  }
}

// l0[b][p][h] = sum_k map_emb[landmarks[b,p,k]][h]  (f16 out)
__global__ __launch_bounds__(256) void l0_kernel(
    const int* __restrict__ lm, const float* __restrict__ me, f16* __restrict__ l0) {
  const int bp = blockIdx.x, tid = threadIdx.x;
  const int h = tid * 4;
  int id[6];
#pragma unroll
  for (int k = 0; k < 6; ++k) id[k] = lm[bp * 6 + k];
  float a0 = 0.f, a1 = 0.f, a2 = 0.f, a3 = 0.f;
#pragma unroll
  for (int k = 0; k < 6; ++k) {
    const float* r = me + id[k] * 1024 + h;
    a0 += r[0]; a1 += r[1]; a2 += r[2]; a3 += r[3];
  }
  union { uint2 u; f16 hh[4]; } pk;
  pk.hh[0] = (f16)a0; pk.hh[1] = (f16)a1; pk.hh[2] = (f16)a2; pk.hh[3] = (f16)a3;
  *(uint2*)&l0[(long)bp * 1024 + h] = pk.u;
}

// patch[(b*16+p)][i*4+tap] = src[b][nbr(p,tap)][i], taps = up,left,right,down
__global__ __launch_bounds__(256) void patch_kernel(
    const f16* __restrict__ src, f16* __restrict__ patch) {
  const int bp = blockIdx.x, tid = threadIdx.x;
  const int b = bp >> 4, p = bp & 15, y = p >> 2, x = p & 3;
  const int base = b * 16;
  f16* pr = patch + (long)bp * 4096;
  for (int i = tid; i < 1024; i += 256) {
    union { uint2 u; f16 h[4]; } pk;
    pk.h[0] = (y > 0) ? src[(long)(base + p - 4) * 1024 + i] : (f16)0.f;
    pk.h[1] = (x > 0) ? src[(long)(base + p - 1) * 1024 + i] : (f16)0.f;
    pk.h[2] = (x < 3) ? src[(long)(base + p + 1) * 1024 + i] : (f16)0.f;
    pk.h[3] = (y < 3) ? src[(long)(base + p + 4) * 1024 + i] : (f16)0.f;
    *(uint2*)&pr[i * 4] = pk.u;
  }
}

// logits -> softmax -> log_softmax(prob) -> loss/acc (atomicAdd into la[2] f32)
__global__ __launch_bounds__(256) void logits_kernel(
    const f16* __restrict__ l0, const f16* __restrict__ l1, const f16* __restrict__ l2,
    const float* __restrict__ msgs, const int* __restrict__ ys, float* __restrict__ la) {
  __shared__ float lg[16];
  const int b = blockIdx.x, tid = threadIdx.x;
  const int p = tid >> 4, q = tid & 15;
  const float* m0 = msgs + b * 1024;
  const float* m1 = msgs + 131072 + b * 1024;
  const float* m2 = msgs + 262144 + b * 1024;
  const long row = (long)(b * 16 + p) * 1024;
  float part = 0.f;
  for (int i = 0; i < 64; ++i) {
    const int h = q + 16 * i;
    part += (float)l0[row + h] * m0[h] + (float)l1[row + h] * m1[h] +
            (float)l2[row + h] * m2[h];
  }
#pragma unroll
  for (int off = 8; off; off >>= 1) part += __shfl_xor(part, off, 16);
  if (q == 0) lg[p] = part;
  __syncthreads();
  if (tid == 0) {
    float mx = lg[0];
    for (int i = 1; i < 16; ++i) mx = fmaxf(mx, lg[i]);
    float pr[16]; float s = 0.f;
    for (int i = 0; i < 16; ++i) { pr[i] = __expf(lg[i] - mx); s += pr[i]; }
    for (int i = 0; i < 16; ++i) pr[i] /= s;
    float mx2 = pr[0];
    for (int i = 1; i < 16; ++i) mx2 = fmaxf(mx2, pr[i]);
    float s2 = 0.f;
    for (int i = 0; i < 16; ++i) s2 += __expf(pr[i] - mx2);
    const float lse = mx2 + __logf(s2);
    const int y = ys[b * 2] * 4 + ys[b * 2 + 1];
    const float logp = pr[y] - lse;
    int am = 0; float bv = pr[0];
    for (int i = 1; i < 16; ++i) if (pr[i] > bv) { bv = pr[i]; am = i; }
    atomicAdd(&la[0], -logp * (1.0f / 128.0f));
    atomicAdd(&la[1], (am == y) ? (1.0f / 128.0f) : 0.0f);
  }
}

// d_out is 2 x FLOAT32 (loss, acc)
__global__ void finalize_kernel(const float* __restrict__ la,
                                float* __restrict__ out) {
  if (threadIdx.x == 0) { out[0] = la[0]; out[1] = la[1]; }
}

// x16[t*128+b][e] = (f16) emb[Xs[b][t]][e]
__global__ __launch_bounds__(256) void embed_kernel(
    const int* __restrict__ Xs, const float* __restrict__ emb, f16* __restrict__ x16) {
  const int m = blockIdx.x, tid = threadIdx.x;
  const int t = m >> 7, b = m & 127;
  const int v = Xs[b * 256 + t];
  const int e = tid * 2;
  const float2 f = *(const float2*)&emb[(long)v * 512 + e];
  *(unsigned*)&x16[(long)m * 512 + e] = pck(f.x, f.y);
}

// post-LSTM weight prep (targets alias the dead x16 region):
// updW16 f16 [1024][2048]; w4 f16 [1024][4096] = cross taps (0,1),(1,0),(1,2),(2,1)
__global__ __launch_bounds__(256) void prep2_kernel(
    const float* __restrict__ upd_W, const float* __restrict__ conv_w,
    f16* __restrict__ updW16, f16* __restrict__ w4) {
  const int idx = blockIdx.x * 256 + threadIdx.x;  // 0..4194303
  if (idx < 2097152) updW16[idx] = (f16)upd_W[idx];
  const int o = idx >> 12, r = idx & 4095, i = r >> 2, tp = r & 3;
  w4[idx] = (f16)conv_w[(long)(o * 1024 + i) * 9 + 1 + 2 * tp];
}

// zero h state / flags / loss accum, init controller = broadcast(feat_ctrl)
__global__ __launch_bounds__(256) void init_kernel(
    f16* __restrict__ hg, int* __restrict__ bar, float* __restrict__ la,
    float* __restrict__ ctrlA, const float* __restrict__ feat) {
  const int idx = blockIdx.x * 256 + threadIdx.x;  // 0..131071
  ((unsigned*)hg)[idx] = 0u;
  ctrlA[idx] = feat[idx & 1023];
  if (idx < 256) bar[idx] = 0;
  if (idx < 2) la[idx] = 0.f;
}

__global__ void fail_kernel(float* out, int mb) {
  if (threadIdx.x == 0) { out[0] = 12344.0f; out[1] = (float)mb; }
}

// ---------------------------------------------------------------------------
extern "C" void kernel_launch(void* const* d_in, const int* in_sizes, int n_in,
                              void* d_out, int out_size, void* d_ws, size_t ws_size,
                              hipStream_t stream) {
  (void)in_sizes; (void)n_in; (void)out_size;
  const int*   Xs      = (const int*)d_in[0];
  const float* seqmask = (const float*)d_in[1];
  const int*   lm      = (const int*)d_in[2];
  const int*   ys      = (const int*)d_in[3];
  const float* emb     = (const float*)d_in[4];
  const float* W_ih_f  = (const float*)d_in[5];
  const float* W_hh_f  = (const float*)d_in[6];
  const float* b_f     = (const float*)d_in[7];
  const float* W_ih_b  = (const float*)d_in[8];
  const float* W_hh_b  = (const float*)d_in[9];
  const float* b_b     = (const float*)d_in[10];
  const float* feat    = (const float*)d_in[11];
  const float* upd_W   = (const float*)d_in[12];
  const float* upd_b   = (const float*)d_in[13];
  const float* mapemb  = (const float*)d_in[14];
  const float* conv_w  = (const float*)d_in[15];
  float* out = (float*)d_out;  // 2 x f32 (loss, acc)
  char* ws = (char*)d_ws;
  size_t off = 0;
  auto alloc = [&](size_t bytes) {
    void* p = ws + off; off += (bytes + 255) & ~(size_t)255; return p;
  };
  f16*   x16    = (f16*)alloc(33554432);   // [t*128+b][512] f16; dead post-LSTM
  f16*   hid    = (f16*)alloc(67108864);   // hidden f16 [b][t][1024]
  f16*   hgb    = (f16*)alloc(524288);     // h state [d][parity][128][512]
  int*   bar    = (int*)alloc(1024);       // flags [d][bg][ug] (monotone)
  float* la     = (float*)alloc(256);      // loss/acc f32 accum
  float* ctrlA  = (float*)alloc(524288);
  float* ctrlB  = (float*)alloc(524288);
  float* msgs   = (float*)alloc(1572864);  // 3 x [128][1024] f32
  f16*   cat    = (f16*)alloc(524288);     // [128][2048] f16
  f16*   l0b    = (f16*)alloc(4194304);    // [b*16+p][1024] f16
  f16*   l1b    = (f16*)alloc(4194304);
  f16*   l2b    = (f16*)alloc(4194304);
  // aliases into the x16 region (only used after the LSTM):
  f16*   patch  = x16;                      // [2048][4096] f16, 16 MB
  f16*   w416   = x16 + 8388608;            // [1024][4096] f16, 8 MB
  f16*   updW16 = x16 + 12582912;           // [1024][2048] f16, 4 MB
  if (ws_size < off) {                      // ~112 MB needed
    fail_kernel<<<1, 64, 0, stream>>>(out, (int)(off >> 20));
    return;
  }

  init_kernel<<<512, 256, 0, stream>>>(hgb, bar, la, ctrlA, feat);
  embed_kernel<<<32768, 256, 0, stream>>>(Xs, emb, x16);
  {
    void* args[] = {(void*)&x16, (void*)&W_ih_f, (void*)&W_ih_b,
                    (void*)&W_hh_f, (void*)&W_hh_b, (void*)&b_f, (void*)&b_b,
                    (void*)&hgb, (void*)&hid, (void*)&bar};
    hipLaunchCooperativeKernel((void*)lstm_kernel, dim3(256), dim3(256), args, 0, stream);
  }
  prep2_kernel<<<16384, 256, 0, stream>>>(upd_W, conv_w, updW16, w416);
  // landmark path
  l0_kernel<<<2048, 256, 0, stream>>>(lm, mapemb, l0b);
  patch_kernel<<<2048, 256, 0, stream>>>(l0b, patch);
  gemm_kernel<<<dim3(16, 8), 256, 0, stream>>>(patch, w416, nullptr, l1b,
                                               2048, 1024, 4096, 1);
  patch_kernel<<<2048, 256, 0, stream>>>(l1b, patch);
  gemm_kernel<<<dim3(16, 8), 256, 0, stream>>>(patch, w416, nullptr, l2b,
                                               2048, 1024, 4096, 1);
  // attention x3 (controller ping-pong); ctrl' = cat @ upd_W^T + upd_b (f32)
  att_kernel<<<128, 256, 0, stream>>>(hid, ctrlA, seqmask, msgs, cat);
  gemm_kernel<<<dim3(1, 8), 256, 0, stream>>>(cat, updW16, upd_b, ctrlB,
                                              128, 1024, 2048, 0);
  att_kernel<<<128, 256, 0, stream>>>(hid, ctrlB, seqmask, msgs + 131072, cat);
  gemm_kernel<<<dim3(1, 8), 256, 0, stream>>>(cat, updW16, upd_b, ctrlA,
                                              128, 1024, 2048, 0);
  att_kernel<<<128, 256, 0, stream>>>(hid, ctrlA, seqmask, msgs + 262144, nullptr);
  logits_kernel<<<128, 256, 0, stream>>>(l0b, l1b, l2b, msgs, ys, la);
  finalize_kernel<<<1, 64, 0, stream>>>(la, out);
}